// Round 9
// baseline (740.162 us; speedup 1.0000x reference)
//
#include <hip/hip_runtime.h>
#include <hip/hip_bf16.h>

#define N_NODES 100000
#define E_EDGES 400000
#define NPAD 100096   // 1564 * 64

typedef unsigned short u16;
typedef __attribute__((ext_vector_type(4))) float f32x4;
typedef __attribute__((ext_vector_type(8))) short bf16x8;

__device__ inline u16 f2b(float v) {
    __hip_bfloat16 h = __float2bfloat16(v);
    return *reinterpret_cast<u16*>(&h);
}
__device__ inline float b2f(u16 u) { return __uint_as_float(((unsigned)u) << 16); }

__device__ inline void gld_lds16(const u16* g, u16* l) {
    __builtin_amdgcn_global_load_lds(
        (const __attribute__((address_space(1))) unsigned*)g,
        (__attribute__((address_space(3))) unsigned*)l, 16, 0, 0);
}

// ---------------- fold W2/b2 into Wcat: Wcat2p[512][256] bf16, bias2[512] f32 ----------
__global__ __launch_bounds__(128) void k_fold(
    const float* __restrict__ W2, const float* __restrict__ Wih,
    const float* __restrict__ Whh, const float* __restrict__ bih,
    const float* __restrict__ bhh, const float* __restrict__ b2,
    u16* __restrict__ Wcat2p, float* __restrict__ bias2) {
    int c = blockIdx.x, t = threadIdx.x;
    __shared__ float wrow[128];
    __shared__ float red[128];
    wrow[t] = (c < 384) ? Wih[c * 128 + t] : 0.f;
    __syncthreads();
    float a = 0.f;
    for (int m = 0; m < 128; ++m) a += W2[t * 128 + m] * wrow[m];
    Wcat2p[c * 256 + t] = f2b(a);
    float dv = (c < 256) ? Whh[c * 128 + t] : (c >= 384 ? Whh[(c - 128) * 128 + t] : 0.f);
    Wcat2p[c * 256 + 128 + t] = f2b(dv);
    red[t] = b2[t] * wrow[t];
    __syncthreads();
    for (int o = 64; o; o >>= 1) { if (t < o) red[t] += red[t + o]; __syncthreads(); }
    if (t == 0) {
        float b = (c < 256) ? bih[c] + bhh[c] + red[0]
                : (c < 384 ? bih[c] + red[0] : bhh[c - 128]);
        bias2[c] = b;
    }
}

// ---------------- pack W1 + proj weights (Wc-fold computed inline) ----------------
__global__ __launch_bounds__(256) void k_pack(
    const float* __restrict__ W1,
    const float* __restrict__ Wq, const float* __restrict__ Wk,
    const float* __restrict__ Wv, const float* __restrict__ Ws,
    const float* __restrict__ Wc,
    const float* __restrict__ bq, const float* __restrict__ bk,
    const float* __restrict__ bv, const float* __restrict__ bs,
    const float* __restrict__ bc,
    u16* __restrict__ W1p, u16* __restrict__ Wprojp, float* __restrict__ bproj) {
    int i = blockIdx.x * 256 + threadIdx.x;
    if (i < 49152) { int n = i / 384, k2 = i % 384; W1p[i] = f2b(W1[k2 * 128 + n]); return; }
    i -= 49152;
    if (i < 98304) {
        int n = i / 128, k2 = i % 128; float v;
        if (n < 256)      v = Wq[k2 * 256 + n];
        else if (n < 512) v = Wk[k2 * 256 + (n - 256)];
        else if (n < 640) {
            int t = n - 512, h = t >> 6, o = t & 63;
            float a = 0.f;
            for (int c = 0; c < 128; ++c) a += Wv[k2 * 256 + h * 128 + c] * Wc[(h * 128 + c) * 64 + o];
            v = a;
        } else if (n < 704) {
            int o = n - 640;
            float a = 0.f;
            for (int j = 0; j < 256; ++j) a += Ws[k2 * 256 + j] * Wc[j * 64 + o];
            v = a;
        } else v = 0.f;
        Wprojp[i] = f2b(v); return;
    }
    i -= 98304;
    if (i < 768) {
        float v;
        if (i < 256)      v = bq[i];
        else if (i < 512) v = bk[i - 256];
        else if (i < 640) {
            int t = i - 512, h = t >> 6, o = t & 63;
            float a = 0.f;
            for (int c = 0; c < 128; ++c) a += bv[h * 128 + c] * Wc[(h * 128 + c) * 64 + o];
            v = a;
        } else if (i < 704) {
            int o = i - 640;
            float a = bc[o];
            for (int j = 0; j < 256; ++j) a += bs[j] * Wc[j * 64 + o];
            v = a;
        } else v = 0.f;
        bproj[i] = v;
    }
}

// ---------------- init ----------------
__global__ void k_init(int* __restrict__ winner, int* __restrict__ deg,
                       int* __restrict__ counters) {
    int n = blockIdx.x * 256 + threadIdx.x;
    if (n == 0) { counters[0] = 0; counters[1] = 0; }  // wcount, etot
    if (n < N_NODES) { winner[n] = -1; deg[n] = 0; }
}

// ---------------- edge pass: winner (max edge idx) + degree histogram ----------------
__global__ void k_edges(const int* __restrict__ ei, int* __restrict__ winner,
                        int* __restrict__ deg) {
    int e = blockIdx.x * 256 + threadIdx.x;
    if (e < E_EDGES) {
        int dst = ei[E_EDGES + e];
        atomicMax(&winner[dst], e);
        atomicAdd(&deg[dst], 1);
    }
}

// -------- node pass: compact winners (node, edge, src triples) + CSR alloc --------
__global__ void k_nodes(const int* __restrict__ winner, const int* __restrict__ deg,
                        const int* __restrict__ ei,
                        int* __restrict__ wnode, int* __restrict__ wedge,
                        int* __restrict__ wsrc, int* __restrict__ counters,
                        int* __restrict__ startA, int* __restrict__ cursor) {
    int n = blockIdx.x * 256 + threadIdx.x;
    if (n >= N_NODES) return;
    int we = winner[n];
    if (we >= 0) {
        int i = atomicAdd(&counters[0], 1);
        wnode[i] = n;
        wedge[i] = we;
        wsrc[i] = ei[we];
    }
    int d = deg[n];
    int st = d ? atomicAdd(&counters[1], d) : 0;
    startA[n] = st;
    cursor[n] = st;
}

// ---------------- fill CSR: segment holds src node of each in-edge ----------------
__global__ void k_fill(const int* __restrict__ ei, int* __restrict__ cursor,
                       int* __restrict__ esrc) {
    int e = blockIdx.x * 256 + threadIdx.x;
    if (e < E_EDGES) {
        int dst = ei[E_EDGES + e];
        int pos = atomicAdd(&cursor[dst], 1);
        esrc[pos] = ei[e];
    }
}

// ---------------- x init (bf16 copy of memory; winner rows overwritten by k_mg) -------
__global__ void k_xinit(const float* __restrict__ mem, const int* __restrict__ winner,
                        u16* __restrict__ x) {
    size_t idx = ((size_t)blockIdx.x * 256 + threadIdx.x) * 4;
    if (idx >= (size_t)N_NODES * 128) return;
    if (winner[idx >> 7] >= 0) return;   // GRU will write this row
    float4 v = *(const float4*)(mem + idx);
    ushort4 o;
    o.x = f2b(v.x); o.y = f2b(v.y); o.z = f2b(v.z); o.w = f2b(v.w);
    *(ushort4*)(x + idx) = o;
}

// ========== fused gather + message-MLP + GRU for winner rows -> xb ==========
// 64 rows/block, 4 waves; swapped-operand MFMA (lane owns one output row).
// Register-demand control WITHOUT min-waves bounds (r7/r8 lesson: AGPRs share
// the unified file; forcing waves/EU>1 against a ~260-reg live set spills
// catastrophically): (a) gather split into afs/afd/afe so only afd (16 regs)
// survives GEMM1; (b) GEMM2 in 2 passes of 2 quadrants (acc2 64 f32);
// (c) r,z packed bf16 in 32 u32. If total demand <=256 HW runs 2 waves/EU.
__global__ __launch_bounds__(256) void k_mg(
    const float* __restrict__ mem, const float* __restrict__ eattr,
    const int* __restrict__ wnode, const int* __restrict__ wedge,
    const int* __restrict__ wsrc, const int* __restrict__ Mp,
    const u16* __restrict__ W1p, const float* __restrict__ b1,
    const u16* __restrict__ Wcat2p, const float* __restrict__ bias2,
    u16* __restrict__ xb) {
    __shared__ u16 lB[2][128 * 64];
    __shared__ u16 h1l[64][136];   // padded rows -> 2-way-free banking

    const int tid = threadIdx.x;
    const int wid = tid >> 6, lane = tid & 63;
    const int lrow = lane & 15, lhi = lane >> 4;
    const int M = *Mp;
    const int arow0 = blockIdx.x * 64;
    if (arow0 >= M) return;

    const int rowg = arow0 + wid * 16 + lrow;
    const int rowc = min(rowg, M - 1);
    const int node = wnode[rowc];
    const int we = wedge[rowc];
    const int src = wsrc[rowc];

    auto ldcvt = [&](const float* p) -> bf16x8 {
        float4 v0 = *(const float4*)p;
        float4 v1 = *(const float4*)(p + 4);
        bf16x8 a;
        a[0] = (short)f2b(v0.x); a[1] = (short)f2b(v0.y);
        a[2] = (short)f2b(v0.z); a[3] = (short)f2b(v0.w);
        a[4] = (short)f2b(v1.x); a[5] = (short)f2b(v1.y);
        a[6] = (short)f2b(v1.z); a[7] = (short)f2b(v1.w);
        return a;
    };
    // gather A fragments; afs/afe die after GEMM1, only afd survives into GEMM2
    bf16x8 afs[4], afd[4], afe[4];
#pragma unroll
    for (int ks = 0; ks < 4; ++ks) afs[ks] = ldcvt(mem + (size_t)src * 128 + (ks * 4 + lhi) * 8);
#pragma unroll
    for (int ks = 0; ks < 4; ++ks) afd[ks] = ldcvt(mem + (size_t)node * 128 + (ks * 4 + lhi) * 8);
#pragma unroll
    for (int ks = 0; ks < 4; ++ks) afe[ks] = ldcvt(eattr + (size_t)we * 128 + (ks * 4 + lhi) * 8);

    auto stB = [&](const u16* Bp, int K, int rowoff, int kt, int buf) {
#pragma unroll
        for (int i = 0; i < 4; ++i) {
            int chunk = i * 256 + wid * 64 + lane;
            int row = chunk >> 3, cc = chunk & 7;
            int ccs = cc ^ (row & 7);
            gld_lds16(Bp + (size_t)(rowoff + row) * K + kt * 64 + ccs * 8,
                      &lB[buf][(i * 256 + wid * 64) * 8]);
        }
    };
    stB(W1p, 384, 0, 0, 0);
    asm volatile("s_waitcnt vmcnt(0)" ::: "memory");
    __syncthreads();

    // ---- GEMM1: h1 = relu([src|dst|eattr] @ W1 + b1), K=384, N=128 ----
    f32x4 acc1[8] = {};
#pragma unroll
    for (int kt = 0; kt < 6; ++kt) {
        if (kt + 1 < 6) stB(W1p, 384, 0, kt + 1, (kt + 1) & 1);
        const u16* lBc = lB[kt & 1];
#pragma unroll
        for (int ks = 0; ks < 2; ++ks) {
            const int ks2 = kt * 2 + ks;
            bf16x8 a = (ks2 < 4) ? afs[ks2] : (ks2 < 8) ? afd[ks2 - 4] : afe[ks2 - 8];
            bf16x8 bf[8];
#pragma unroll
            for (int n2 = 0; n2 < 8; ++n2) {
                int chunk = (ks * 4 + lhi) ^ (lrow & 7);
                bf[n2] = *(const bf16x8*)&lBc[(size_t)(n2 * 16 + lrow) * 64 + chunk * 8];
            }
#pragma unroll
            for (int n2 = 0; n2 < 8; ++n2)
                acc1[n2] = __builtin_amdgcn_mfma_f32_16x16x32_bf16(
                    bf[n2], a, acc1[n2], 0, 0, 0);
        }
        asm volatile("s_waitcnt vmcnt(0)" ::: "memory");
        __syncthreads();
    }

    // stage GEMM2 tile 0 while h1 goes to LDS
    stB(Wcat2p, 256, 0, 0, 0);
    {
        const int rl = wid * 16 + lrow;
#pragma unroll
        for (int n2 = 0; n2 < 8; ++n2) {
            int col = n2 * 16 + lhi * 4;
            float4 bv = *(const float4*)&b1[col];
            ushort4 o;
            o.x = f2b(fmaxf(acc1[n2][0] + bv.x, 0.f));
            o.y = f2b(fmaxf(acc1[n2][1] + bv.y, 0.f));
            o.z = f2b(fmaxf(acc1[n2][2] + bv.z, 0.f));
            o.w = f2b(fmaxf(acc1[n2][3] + bv.w, 0.f));
            *(ushort4*)&h1l[rl][col] = o;
        }
    }
    asm volatile("s_waitcnt vmcnt(0)" ::: "memory");
    __syncthreads();

    // A-fragments for GEMM2: k<128 from h1 (LDS), k>=128 = dst half = afd
    bf16x8 af2[4];
#pragma unroll
    for (int ks = 0; ks < 4; ++ks)
        af2[ks] = *(const bf16x8*)&h1l[wid * 16 + lrow][ks * 32 + lhi * 8];

    // ---- GEMM2: 16 tiles (quad = t>>2); acc holds 2 quads; rz packed at t==7 ----
    f32x4 acc2[2][8] = {};
    unsigned rz[32];
#pragma unroll
    for (int t = 0; t < 16; ++t) {
        const int qq = (t >> 2) & 1;
        if (t + 1 < 16) stB(Wcat2p, 256, ((t + 1) >> 2) * 128, (t + 1) & 3, (t + 1) & 1);
        const u16* lBc = lB[t & 1];
#pragma unroll
        for (int ks = 0; ks < 2; ++ks) {
            const int ks2 = (t & 3) * 2 + ks;
            bf16x8 a = (ks2 < 4) ? af2[ks2] : afd[ks2 - 4];
            bf16x8 bf[8];
#pragma unroll
            for (int n2 = 0; n2 < 8; ++n2) {
                int chunk = (ks * 4 + lhi) ^ (lrow & 7);
                bf[n2] = *(const bf16x8*)&lBc[(size_t)(n2 * 16 + lrow) * 64 + chunk * 8];
            }
#pragma unroll
            for (int n2 = 0; n2 < 8; ++n2)
                acc2[qq][n2] = __builtin_amdgcn_mfma_f32_16x16x32_bf16(
                    bf[n2], a, acc2[qq][n2], 0, 0, 0);
        }
        asm volatile("s_waitcnt vmcnt(0)" ::: "memory");
        __syncthreads();
        if (t == 7) {
            // pass 0 done: r = sigmoid(R), z = sigmoid(Z) -> packed bf16 pairs
#pragma unroll
            for (int n2 = 0; n2 < 8; ++n2) {
                int col = n2 * 16 + lhi * 4;
                float4 br = *(const float4*)&bias2[col];
                float4 bz = *(const float4*)&bias2[128 + col];
#pragma unroll
                for (int j = 0; j < 4; ++j) {
                    float bR = (j == 0) ? br.x : (j == 1) ? br.y : (j == 2) ? br.z : br.w;
                    float bZ = (j == 0) ? bz.x : (j == 1) ? bz.y : (j == 2) ? bz.z : bz.w;
                    float r = 1.f / (1.f + expf(-(acc2[0][n2][j] + bR)));
                    float z = 1.f / (1.f + expf(-(acc2[1][n2][j] + bZ)));
                    rz[n2 * 4 + j] = (unsigned)f2b(r) | ((unsigned)f2b(z) << 16);
                }
                acc2[0][n2] = (f32x4){0.f, 0.f, 0.f, 0.f};
                acc2[1][n2] = (f32x4){0.f, 0.f, 0.f, 0.f};
            }
        }
    }

    // ---- GRU epilogue -> xb[node] (acc2[0]=IN, acc2[1]=HN) ----
    if (rowg >= M) return;
#pragma unroll
    for (int n2 = 0; n2 < 8; ++n2) {
        int col = n2 * 16 + lhi * 4;
        float4 bn = *(const float4*)&bias2[256 + col];
        float4 bh = *(const float4*)&bias2[384 + col];
        float4 hv = *(const float4*)&mem[(size_t)node * 128 + col];
        ushort4 o;
#pragma unroll
        for (int j = 0; j < 4; ++j) {
            float bN = (j == 0) ? bn.x : (j == 1) ? bn.y : (j == 2) ? bn.z : bn.w;
            float bH = (j == 0) ? bh.x : (j == 1) ? bh.y : (j == 2) ? bh.z : bh.w;
            float hj = (j == 0) ? hv.x : (j == 1) ? hv.y : (j == 2) ? hv.z : hv.w;
            unsigned p = rz[n2 * 4 + j];
            float r = b2f((u16)(p & 0xffff));
            float z = b2f((u16)(p >> 16));
            float n = tanhf(acc2[0][n2][j] + bN + r * (acc2[1][n2][j] + bH));
            u16 res = f2b((1.f - z) * n + z * hj);
            if (j == 0) o.x = res; else if (j == 1) o.y = res;
            else if (j == 2) o.z = res; else o.w = res;
        }
        *(ushort4*)&xb[(size_t)node * 128 + col] = o;
    }
}

// ================= proj GEMM: K=128, 6 quads in 2 passes of 3 (acc 96 f32) ==========
__global__ __launch_bounds__(256) void k_proj(
    const u16* __restrict__ A, const u16* __restrict__ Bp,
    const float* __restrict__ bias, int Mmax,
    u16* __restrict__ qb, u16* __restrict__ kb, u16* __restrict__ vcb,
    float* __restrict__ outf) {
    __shared__ u16 lA[64 * 128];
    __shared__ u16 lB[2][128 * 64];

    const int tid = threadIdx.x;
    const int wid = tid >> 6, lane = tid & 63;
    const int lrow = lane & 15, lhi = lane >> 4;
    const int arow0 = blockIdx.x * 64;

#pragma unroll
    for (int i = 0; i < 4; ++i) {
        int chunk = i * 256 + wid * 64 + lane;
        int row = chunk >> 4, cc = chunk & 15;
        int ccs = (cc & ~7) | ((cc ^ row) & 7);
        gld_lds16(A + (size_t)(arow0 + row) * 128 + ccs * 8, &lA[(i * 256 + wid * 64) * 8]);
    }
    auto stageB = [&](int t, int buf) {
        int q = t >> 1, kt = t & 1;
#pragma unroll
        for (int i = 0; i < 4; ++i) {
            int chunk = i * 256 + wid * 64 + lane;
            int row = chunk >> 3, cc = chunk & 7;
            int ccs = cc ^ (row & 7);
            gld_lds16(Bp + (size_t)(q * 128 + row) * 128 + kt * 64 + ccs * 8,
                      &lB[buf][(i * 256 + wid * 64) * 8]);
        }
    };
    stageB(0, 0);
    asm volatile("s_waitcnt vmcnt(0)" ::: "memory");
    __syncthreads();

    bf16x8 af[4];
#pragma unroll
    for (int ks = 0; ks < 4; ++ks) {
        int chunk = ks * 4 + lhi;
        int ccs = (chunk & ~7) | ((chunk ^ lrow) & 7);
        af[ks] = *(const bf16x8*)&lA[(size_t)(wid * 16 + lrow) * 128 + ccs * 8];
    }

    const int rowg = arow0 + wid * 16 + lrow;
    auto storeq = [&](int q, f32x4 (&aq)[8]) {
        if (rowg >= Mmax) return;
#pragma unroll
        for (int n2 = 0; n2 < 8; ++n2) {
            int colg = q * 128 + n2 * 16 + lhi * 4;
            if (colg >= 704) continue;
            float4 bv = *(const float4*)&bias[colg];
            float v0 = aq[n2][0] + bv.x, v1 = aq[n2][1] + bv.y;
            float v2 = aq[n2][2] + bv.z, v3 = aq[n2][3] + bv.w;
            if (colg < 640) {
                ushort4 o;
                o.x = f2b(v0); o.y = f2b(v1); o.z = f2b(v2); o.w = f2b(v3);
                if (colg < 256)
                    *(ushort4*)&qb[(size_t)rowg * 256 + colg] = o;
                else if (colg < 512)
                    *(ushort4*)&kb[(size_t)rowg * 256 + (colg - 256)] = o;
                else
                    *(ushort4*)&vcb[(size_t)rowg * 128 + (colg - 512)] = o;
            } else {
                float4 o; o.x = v0; o.y = v1; o.z = v2; o.w = v3;
                *(float4*)&outf[(size_t)rowg * 64 + (colg - 640)] = o;
            }
        }
    };

    f32x4 acc[3][8] = {};
#pragma unroll
    for (int t = 0; t < 12; ++t) {
        const int qq = (t >> 1) % 3;
        if (t + 1 < 12) stageB(t + 1, (t + 1) & 1);
        const u16* lBc = lB[t & 1];
#pragma unroll
        for (int ks = 0; ks < 2; ++ks) {
            bf16x8 bf[8];
#pragma unroll
            for (int n2 = 0; n2 < 8; ++n2) {
                int chunk = (ks * 4 + lhi) ^ (lrow & 7);
                bf[n2] = *(const bf16x8*)&lBc[(size_t)(n2 * 16 + lrow) * 64 + chunk * 8];
            }
#pragma unroll
            for (int n2 = 0; n2 < 8; ++n2)
                acc[qq][n2] = __builtin_amdgcn_mfma_f32_16x16x32_bf16(
                    bf[n2], af[(t & 1) * 2 + ks], acc[qq][n2], 0, 0, 0);
        }
        asm volatile("s_waitcnt vmcnt(0)" ::: "memory");
        __syncthreads();
        if (t == 5) {
            storeq(0, acc[0]); storeq(1, acc[1]); storeq(2, acc[2]);
#pragma unroll
            for (int q2 = 0; q2 < 3; ++q2)
#pragma unroll
                for (int n2 = 0; n2 < 8; ++n2)
                    acc[q2][n2] = (f32x4){0.f, 0.f, 0.f, 0.f};
        }
    }
    storeq(3, acc[0]); storeq(4, acc[1]); storeq(5, acc[2]);
}

// ---------------- CSR attention: one wave per dst, no atomics ----------------
__global__ __launch_bounds__(256) void k_attn(
    const u16* __restrict__ qB, const u16* __restrict__ kB, const u16* __restrict__ vcB,
    const int* __restrict__ startA, const int* __restrict__ deg,
    const int* __restrict__ esrc, float* __restrict__ out) {
    int wid = threadIdx.x >> 6, lane = threadIdx.x & 63;
    int dst = blockIdx.x * 4 + wid;
    if (dst >= N_NODES) return;
    int d = deg[dst];
    if (d == 0) return;
    int st = startA[dst];

    ushort4 qv = *(const ushort4*)&qB[(size_t)dst * 256 + lane * 4];
    float q0 = b2f(qv.x), q1 = b2f(qv.y), q2 = b2f(qv.z), q3 = b2f(qv.w);
    const float inv = 0.08838834764831845f;  // 1/sqrt(128)

    float s0 = 0.f, s1 = 0.f, accA = 0.f, accB = 0.f;
    for (int p = st; p < st + d; ++p) {
        int src = esrc[p];
        ushort4 kv = *(const ushort4*)&kB[(size_t)src * 256 + lane * 4];
        float pp = q0 * b2f(kv.x) + q1 * b2f(kv.y) + q2 * b2f(kv.z) + q3 * b2f(kv.w);
        pp += __shfl_xor(pp, 1);
        pp += __shfl_xor(pp, 2);
        pp += __shfl_xor(pp, 4);
        pp += __shfl_xor(pp, 8);
        pp += __shfl_xor(pp, 16);
        float e = expf(pp * inv);
        float eo = __shfl_xor(e, 32);
        float e0 = (lane < 32) ? e : eo;
        float e1 = (lane < 32) ? eo : e;
        s0 += e0; s1 += e1;
        float v0 = b2f(vcB[(size_t)src * 128 + lane]);
        float v1 = b2f(vcB[(size_t)src * 128 + 64 + lane]);
        accA += e0 * v0;
        accB += e1 * v1;
    }
    float* op = out + (size_t)dst * 64 + lane;
    *op += accA / s0 + accB / s1;
}

extern "C" void kernel_launch(void* const* d_in, const int* in_sizes, int n_in,
                              void* d_out, int out_size, void* d_ws, size_t ws_size,
                              hipStream_t stream) {
    const float* memory = (const float*)d_in[0];
    const float* W1 = (const float*)d_in[1];  const float* b1 = (const float*)d_in[2];
    const float* W2 = (const float*)d_in[3];  const float* b2 = (const float*)d_in[4];
    const float* Wih = (const float*)d_in[5]; const float* Whh = (const float*)d_in[6];
    const float* bih = (const float*)d_in[7]; const float* bhh = (const float*)d_in[8];
    const float* Wq = (const float*)d_in[9];  const float* bq = (const float*)d_in[10];
    const float* Wk = (const float*)d_in[11]; const float* bk = (const float*)d_in[12];
    const float* Wv = (const float*)d_in[13]; const float* bv = (const float*)d_in[14];
    const float* Ws = (const float*)d_in[15]; const float* bs = (const float*)d_in[16];
    const float* Wc = (const float*)d_in[17]; const float* bc = (const float*)d_in[18];
    const float* eattr = (const float*)d_in[19];
    const int* ei = (const int*)d_in[21];
    float* out = (float*)d_out;

    char* ws = (char*)d_ws;
    size_t off = 0;
    auto alloc = [&](size_t bytes) -> char* {
        char* p = ws + off;
        off = (off + bytes + 255) & ~(size_t)255;
        return p;
    };
    u16* xb = (u16*)alloc((size_t)NPAD * 128 * 2);
    u16* qb = (u16*)alloc((size_t)NPAD * 256 * 2);
    u16* kb = (u16*)alloc((size_t)NPAD * 256 * 2);
    u16* vcb = (u16*)alloc((size_t)NPAD * 128 * 2);
    int* winner = (int*)alloc((size_t)N_NODES * 4);
    int* wnode = (int*)alloc((size_t)N_NODES * 4);
    int* wedge = (int*)alloc((size_t)N_NODES * 4);
    int* wsrc = (int*)alloc((size_t)N_NODES * 4);
    int* deg = (int*)alloc((size_t)N_NODES * 4);
    int* startA = (int*)alloc((size_t)N_NODES * 4);
    int* cursor = (int*)alloc((size_t)N_NODES * 4);
    int* esrc = (int*)alloc((size_t)E_EDGES * 4);
    int* counters = (int*)alloc(256);
    u16* W1p = (u16*)alloc(49152 * 2);
    u16* Wcat2p = (u16*)alloc(131072 * 2);
    u16* Wprojp = (u16*)alloc(98304 * 2);
    float* bias2 = (float*)alloc(512 * 4);
    float* bproj = (float*)alloc(768 * 4);
    (void)ws_size; (void)in_sizes; (void)n_in; (void)out_size;

    int* wcount = counters;  // counters[0]=wcount, counters[1]=etot

    hipLaunchKernelGGL(k_init, dim3(391), dim3(256), 0, stream, winner, deg, counters);
    hipLaunchKernelGGL(k_edges, dim3(1563), dim3(256), 0, stream, ei, winner, deg);
    hipLaunchKernelGGL(k_nodes, dim3(391), dim3(256), 0, stream,
                       winner, deg, ei, wnode, wedge, wsrc, counters, startA, cursor);
    hipLaunchKernelGGL(k_fill, dim3(1563), dim3(256), 0, stream, ei, cursor, esrc);
    hipLaunchKernelGGL(k_pack, dim3(579), dim3(256), 0, stream,
                       W1, Wq, Wk, Wv, Ws, Wc, bq, bk, bv, bs, bc, W1p, Wprojp, bproj);
    hipLaunchKernelGGL(k_fold, dim3(512), dim3(128), 0, stream,
                       W2, Wih, Whh, bih, bhh, b2, Wcat2p, bias2);
    hipLaunchKernelGGL(k_xinit, dim3(12500), dim3(256), 0, stream, memory, winner, xb);
    // fused gather + MLP + GRU for winner rows
    hipLaunchKernelGGL(k_mg, dim3(1564), dim3(256), 0, stream,
                       memory, eattr, wnode, wedge, wsrc, wcount,
                       W1p, b1, Wcat2p, bias2, xb);
    // proj: [q|k|vc|skip] = xb @ Wproj + bproj  (skip -> out, f32)
    hipLaunchKernelGGL(k_proj, dim3(1564), dim3(256), 0, stream,
                       xb, Wprojp, bproj, N_NODES, qb, kb, vcb, out);
    // CSR attention: out[dst] += sum(alpha * vc[src]) per head, no atomics
    hipLaunchKernelGGL(k_attn, dim3(25000), dim3(256), 0, stream,
                       qb, kb, vcb, startA, deg, esrc, out);
}

// Round 10
// 739.900 us; speedup vs baseline: 1.0004x; 1.0004x over previous
//
#include <hip/hip_runtime.h>
#include <hip/hip_bf16.h>

#define N_NODES 100000
#define E_EDGES 400000
#define NPAD 100096   // 1564 * 64

typedef unsigned short u16;
typedef __attribute__((ext_vector_type(4))) float f32x4;
typedef __attribute__((ext_vector_type(8))) short bf16x8;

__device__ inline u16 f2b(float v) {
    __hip_bfloat16 h = __float2bfloat16(v);
    return *reinterpret_cast<u16*>(&h);
}
__device__ inline float b2f(u16 u) { return __uint_as_float(((unsigned)u) << 16); }

__device__ inline void gld_lds16(const u16* g, u16* l) {
    __builtin_amdgcn_global_load_lds(
        (const __attribute__((address_space(1))) unsigned*)g,
        (__attribute__((address_space(3))) unsigned*)l, 16, 0, 0);
}

// ---------------- fold W2/b2 into Wcat: Wcat2p[512][256] bf16, bias2[512] f32 ----------
__global__ __launch_bounds__(128) void k_fold(
    const float* __restrict__ W2, const float* __restrict__ Wih,
    const float* __restrict__ Whh, const float* __restrict__ bih,
    const float* __restrict__ bhh, const float* __restrict__ b2,
    u16* __restrict__ Wcat2p, float* __restrict__ bias2) {
    int c = blockIdx.x, t = threadIdx.x;
    __shared__ float wrow[128];
    __shared__ float red[128];
    wrow[t] = (c < 384) ? Wih[c * 128 + t] : 0.f;
    __syncthreads();
    float a = 0.f;
    for (int m = 0; m < 128; ++m) a += W2[t * 128 + m] * wrow[m];
    Wcat2p[c * 256 + t] = f2b(a);
    float dv = (c < 256) ? Whh[c * 128 + t] : (c >= 384 ? Whh[(c - 128) * 128 + t] : 0.f);
    Wcat2p[c * 256 + 128 + t] = f2b(dv);
    red[t] = b2[t] * wrow[t];
    __syncthreads();
    for (int o = 64; o; o >>= 1) { if (t < o) red[t] += red[t + o]; __syncthreads(); }
    if (t == 0) {
        float b = (c < 256) ? bih[c] + bhh[c] + red[0]
                : (c < 384 ? bih[c] + red[0] : bhh[c - 128]);
        bias2[c] = b;
    }
}

// ---------------- pack W1 + proj weights (Wc-fold computed inline) ----------------
__global__ __launch_bounds__(256) void k_pack(
    const float* __restrict__ W1,
    const float* __restrict__ Wq, const float* __restrict__ Wk,
    const float* __restrict__ Wv, const float* __restrict__ Ws,
    const float* __restrict__ Wc,
    const float* __restrict__ bq, const float* __restrict__ bk,
    const float* __restrict__ bv, const float* __restrict__ bs,
    const float* __restrict__ bc,
    u16* __restrict__ W1p, u16* __restrict__ Wprojp, float* __restrict__ bproj) {
    int i = blockIdx.x * 256 + threadIdx.x;
    if (i < 49152) { int n = i / 384, k2 = i % 384; W1p[i] = f2b(W1[k2 * 128 + n]); return; }
    i -= 49152;
    if (i < 98304) {
        int n = i / 128, k2 = i % 128; float v;
        if (n < 256)      v = Wq[k2 * 256 + n];
        else if (n < 512) v = Wk[k2 * 256 + (n - 256)];
        else if (n < 640) {
            int t = n - 512, h = t >> 6, o = t & 63;
            float a = 0.f;
            for (int c = 0; c < 128; ++c) a += Wv[k2 * 256 + h * 128 + c] * Wc[(h * 128 + c) * 64 + o];
            v = a;
        } else if (n < 704) {
            int o = n - 640;
            float a = 0.f;
            for (int j = 0; j < 256; ++j) a += Ws[k2 * 256 + j] * Wc[j * 64 + o];
            v = a;
        } else v = 0.f;
        Wprojp[i] = f2b(v); return;
    }
    i -= 98304;
    if (i < 768) {
        float v;
        if (i < 256)      v = bq[i];
        else if (i < 512) v = bk[i - 256];
        else if (i < 640) {
            int t = i - 512, h = t >> 6, o = t & 63;
            float a = 0.f;
            for (int c = 0; c < 128; ++c) a += bv[h * 128 + c] * Wc[(h * 128 + c) * 64 + o];
            v = a;
        } else if (i < 704) {
            int o = i - 640;
            float a = bc[o];
            for (int j = 0; j < 256; ++j) a += bs[j] * Wc[j * 64 + o];
            v = a;
        } else v = 0.f;
        bproj[i] = v;
    }
}

// ---------------- init ----------------
__global__ void k_init(int* __restrict__ winner, int* __restrict__ deg,
                       int* __restrict__ counters) {
    int n = blockIdx.x * 256 + threadIdx.x;
    if (n == 0) { counters[0] = 0; counters[1] = 0; }  // wcount, etot
    if (n < N_NODES) { winner[n] = -1; deg[n] = 0; }
}

// ---------------- edge pass: winner (max edge idx) + degree histogram ----------------
__global__ void k_edges(const int* __restrict__ ei, int* __restrict__ winner,
                        int* __restrict__ deg) {
    int e = blockIdx.x * 256 + threadIdx.x;
    if (e < E_EDGES) {
        int dst = ei[E_EDGES + e];
        atomicMax(&winner[dst], e);
        atomicAdd(&deg[dst], 1);
    }
}

// -------- node pass: compact winners (node, edge, src triples) + CSR alloc --------
__global__ void k_nodes(const int* __restrict__ winner, const int* __restrict__ deg,
                        const int* __restrict__ ei,
                        int* __restrict__ wnode, int* __restrict__ wedge,
                        int* __restrict__ wsrc, int* __restrict__ counters,
                        int* __restrict__ startA, int* __restrict__ cursor) {
    int n = blockIdx.x * 256 + threadIdx.x;
    if (n >= N_NODES) return;
    int we = winner[n];
    if (we >= 0) {
        int i = atomicAdd(&counters[0], 1);
        wnode[i] = n;
        wedge[i] = we;
        wsrc[i] = ei[we];
    }
    int d = deg[n];
    int st = d ? atomicAdd(&counters[1], d) : 0;
    startA[n] = st;
    cursor[n] = st;
}

// ---------------- fill CSR: segment holds src node of each in-edge ----------------
__global__ void k_fill(const int* __restrict__ ei, int* __restrict__ cursor,
                       int* __restrict__ esrc) {
    int e = blockIdx.x * 256 + threadIdx.x;
    if (e < E_EDGES) {
        int dst = ei[E_EDGES + e];
        int pos = atomicAdd(&cursor[dst], 1);
        esrc[pos] = ei[e];
    }
}

// ---------------- x init (bf16 copy of memory; winner rows overwritten by k_mg) -------
__global__ void k_xinit(const float* __restrict__ mem, const int* __restrict__ winner,
                        u16* __restrict__ x) {
    size_t idx = ((size_t)blockIdx.x * 256 + threadIdx.x) * 4;
    if (idx >= (size_t)N_NODES * 128) return;
    if (winner[idx >> 7] >= 0) return;   // GRU will write this row
    float4 v = *(const float4*)(mem + idx);
    ushort4 o;
    o.x = f2b(v.x); o.y = f2b(v.y); o.z = f2b(v.z); o.w = f2b(v.w);
    *(ushort4*)(x + idx) = o;
}

// ========== fused gather + message-MLP + GRU for winner rows -> xb ==========
// 64 rows/block, 4 waves; swapped-operand MFMA (lane owns one output row).
// Register discipline (r6-r9 evidence): ONLY an explicit __launch_bounds__(256,1)
// avoids spill on gfx950 (r9: bare (256) defaults to a high-occupancy target,
// VGPR 88 + 626MB scratch; r7/r8: (256,3)/(256,2) likewise spill). With the
// 512-reg budget the allocator never spills; demand cuts (afs/afd/afe split,
// 2-pass acc2, rz bf16-packing) aim the actual allocation <=256 so HW runs
// 2 waves/EU naturally.
__global__ __launch_bounds__(256, 1) void k_mg(
    const float* __restrict__ mem, const float* __restrict__ eattr,
    const int* __restrict__ wnode, const int* __restrict__ wedge,
    const int* __restrict__ wsrc, const int* __restrict__ Mp,
    const u16* __restrict__ W1p, const float* __restrict__ b1,
    const u16* __restrict__ Wcat2p, const float* __restrict__ bias2,
    u16* __restrict__ xb) {
    __shared__ u16 lB[2][128 * 64];
    __shared__ u16 h1l[64][136];   // padded rows -> 2-way-free banking

    const int tid = threadIdx.x;
    const int wid = tid >> 6, lane = tid & 63;
    const int lrow = lane & 15, lhi = lane >> 4;
    const int M = *Mp;
    const int arow0 = blockIdx.x * 64;
    if (arow0 >= M) return;

    const int rowg = arow0 + wid * 16 + lrow;
    const int rowc = min(rowg, M - 1);
    const int node = wnode[rowc];
    const int we = wedge[rowc];
    const int src = wsrc[rowc];

    auto ldcvt = [&](const float* p) -> bf16x8 {
        float4 v0 = *(const float4*)p;
        float4 v1 = *(const float4*)(p + 4);
        bf16x8 a;
        a[0] = (short)f2b(v0.x); a[1] = (short)f2b(v0.y);
        a[2] = (short)f2b(v0.z); a[3] = (short)f2b(v0.w);
        a[4] = (short)f2b(v1.x); a[5] = (short)f2b(v1.y);
        a[6] = (short)f2b(v1.z); a[7] = (short)f2b(v1.w);
        return a;
    };
    // gather A fragments; afs/afe die after GEMM1, only afd survives into GEMM2
    bf16x8 afs[4], afd[4], afe[4];
#pragma unroll
    for (int ks = 0; ks < 4; ++ks) afs[ks] = ldcvt(mem + (size_t)src * 128 + (ks * 4 + lhi) * 8);
#pragma unroll
    for (int ks = 0; ks < 4; ++ks) afd[ks] = ldcvt(mem + (size_t)node * 128 + (ks * 4 + lhi) * 8);
#pragma unroll
    for (int ks = 0; ks < 4; ++ks) afe[ks] = ldcvt(eattr + (size_t)we * 128 + (ks * 4 + lhi) * 8);

    auto stB = [&](const u16* Bp, int K, int rowoff, int kt, int buf) {
#pragma unroll
        for (int i = 0; i < 4; ++i) {
            int chunk = i * 256 + wid * 64 + lane;
            int row = chunk >> 3, cc = chunk & 7;
            int ccs = cc ^ (row & 7);
            gld_lds16(Bp + (size_t)(rowoff + row) * K + kt * 64 + ccs * 8,
                      &lB[buf][(i * 256 + wid * 64) * 8]);
        }
    };
    stB(W1p, 384, 0, 0, 0);
    asm volatile("s_waitcnt vmcnt(0)" ::: "memory");
    __syncthreads();

    // ---- GEMM1: h1 = relu([src|dst|eattr] @ W1 + b1), K=384, N=128 ----
    f32x4 acc1[8] = {};
#pragma unroll
    for (int kt = 0; kt < 6; ++kt) {
        if (kt + 1 < 6) stB(W1p, 384, 0, kt + 1, (kt + 1) & 1);
        const u16* lBc = lB[kt & 1];
#pragma unroll
        for (int ks = 0; ks < 2; ++ks) {
            const int ks2 = kt * 2 + ks;
            bf16x8 a = (ks2 < 4) ? afs[ks2] : (ks2 < 8) ? afd[ks2 - 4] : afe[ks2 - 8];
            bf16x8 bf[8];
#pragma unroll
            for (int n2 = 0; n2 < 8; ++n2) {
                int chunk = (ks * 4 + lhi) ^ (lrow & 7);
                bf[n2] = *(const bf16x8*)&lBc[(size_t)(n2 * 16 + lrow) * 64 + chunk * 8];
            }
#pragma unroll
            for (int n2 = 0; n2 < 8; ++n2)
                acc1[n2] = __builtin_amdgcn_mfma_f32_16x16x32_bf16(
                    bf[n2], a, acc1[n2], 0, 0, 0);
        }
        asm volatile("s_waitcnt vmcnt(0)" ::: "memory");
        __syncthreads();
    }

    // stage GEMM2 tile 0 while h1 goes to LDS
    stB(Wcat2p, 256, 0, 0, 0);
    {
        const int rl = wid * 16 + lrow;
#pragma unroll
        for (int n2 = 0; n2 < 8; ++n2) {
            int col = n2 * 16 + lhi * 4;
            float4 bv = *(const float4*)&b1[col];
            ushort4 o;
            o.x = f2b(fmaxf(acc1[n2][0] + bv.x, 0.f));
            o.y = f2b(fmaxf(acc1[n2][1] + bv.y, 0.f));
            o.z = f2b(fmaxf(acc1[n2][2] + bv.z, 0.f));
            o.w = f2b(fmaxf(acc1[n2][3] + bv.w, 0.f));
            *(ushort4*)&h1l[rl][col] = o;
        }
    }
    asm volatile("s_waitcnt vmcnt(0)" ::: "memory");
    __syncthreads();

    // A-fragments for GEMM2: k<128 from h1 (LDS), k>=128 = dst half = afd
    bf16x8 af2[4];
#pragma unroll
    for (int ks = 0; ks < 4; ++ks)
        af2[ks] = *(const bf16x8*)&h1l[wid * 16 + lrow][ks * 32 + lhi * 8];

    // ---- GEMM2: 16 tiles (quad = t>>2); acc holds 2 quads; rz packed at t==7 ----
    f32x4 acc2[2][8] = {};
    unsigned rz[32];
#pragma unroll
    for (int t = 0; t < 16; ++t) {
        const int qq = (t >> 2) & 1;
        if (t + 1 < 16) stB(Wcat2p, 256, ((t + 1) >> 2) * 128, (t + 1) & 3, (t + 1) & 1);
        const u16* lBc = lB[t & 1];
#pragma unroll
        for (int ks = 0; ks < 2; ++ks) {
            const int ks2 = (t & 3) * 2 + ks;
            bf16x8 a = (ks2 < 4) ? af2[ks2] : afd[ks2 - 4];
            bf16x8 bf[8];
#pragma unroll
            for (int n2 = 0; n2 < 8; ++n2) {
                int chunk = (ks * 4 + lhi) ^ (lrow & 7);
                bf[n2] = *(const bf16x8*)&lBc[(size_t)(n2 * 16 + lrow) * 64 + chunk * 8];
            }
#pragma unroll
            for (int n2 = 0; n2 < 8; ++n2)
                acc2[qq][n2] = __builtin_amdgcn_mfma_f32_16x16x32_bf16(
                    bf[n2], a, acc2[qq][n2], 0, 0, 0);
        }
        asm volatile("s_waitcnt vmcnt(0)" ::: "memory");
        __syncthreads();
        if (t == 7) {
            // pass 0 done: r = sigmoid(R), z = sigmoid(Z) -> packed bf16 pairs
#pragma unroll
            for (int n2 = 0; n2 < 8; ++n2) {
                int col = n2 * 16 + lhi * 4;
                float4 br = *(const float4*)&bias2[col];
                float4 bz = *(const float4*)&bias2[128 + col];
#pragma unroll
                for (int j = 0; j < 4; ++j) {
                    float bR = (j == 0) ? br.x : (j == 1) ? br.y : (j == 2) ? br.z : br.w;
                    float bZ = (j == 0) ? bz.x : (j == 1) ? bz.y : (j == 2) ? bz.z : bz.w;
                    float r = 1.f / (1.f + expf(-(acc2[0][n2][j] + bR)));
                    float z = 1.f / (1.f + expf(-(acc2[1][n2][j] + bZ)));
                    rz[n2 * 4 + j] = (unsigned)f2b(r) | ((unsigned)f2b(z) << 16);
                }
                acc2[0][n2] = (f32x4){0.f, 0.f, 0.f, 0.f};
                acc2[1][n2] = (f32x4){0.f, 0.f, 0.f, 0.f};
            }
        }
    }

    // ---- GRU epilogue -> xb[node] (acc2[0]=IN, acc2[1]=HN) ----
    if (rowg >= M) return;
#pragma unroll
    for (int n2 = 0; n2 < 8; ++n2) {
        int col = n2 * 16 + lhi * 4;
        float4 bn = *(const float4*)&bias2[256 + col];
        float4 bh = *(const float4*)&bias2[384 + col];
        float4 hv = *(const float4*)&mem[(size_t)node * 128 + col];
        ushort4 o;
#pragma unroll
        for (int j = 0; j < 4; ++j) {
            float bN = (j == 0) ? bn.x : (j == 1) ? bn.y : (j == 2) ? bn.z : bn.w;
            float bH = (j == 0) ? bh.x : (j == 1) ? bh.y : (j == 2) ? bh.z : bh.w;
            float hj = (j == 0) ? hv.x : (j == 1) ? hv.y : (j == 2) ? hv.z : hv.w;
            unsigned p = rz[n2 * 4 + j];
            float r = b2f((u16)(p & 0xffff));
            float z = b2f((u16)(p >> 16));
            float n = tanhf(acc2[0][n2][j] + bN + r * (acc2[1][n2][j] + bH));
            u16 res = f2b((1.f - z) * n + z * hj);
            if (j == 0) o.x = res; else if (j == 1) o.y = res;
            else if (j == 2) o.z = res; else o.w = res;
        }
        *(ushort4*)&xb[(size_t)node * 128 + col] = o;
    }
}

// ================= proj GEMM: K=128, 6 quads in 2 passes of 3 (acc 96 f32) ==========
__global__ __launch_bounds__(256, 1) void k_proj(
    const u16* __restrict__ A, const u16* __restrict__ Bp,
    const float* __restrict__ bias, int Mmax,
    u16* __restrict__ qb, u16* __restrict__ kb, u16* __restrict__ vcb,
    float* __restrict__ outf) {
    __shared__ u16 lA[64 * 128];
    __shared__ u16 lB[2][128 * 64];

    const int tid = threadIdx.x;
    const int wid = tid >> 6, lane = tid & 63;
    const int lrow = lane & 15, lhi = lane >> 4;
    const int arow0 = blockIdx.x * 64;

#pragma unroll
    for (int i = 0; i < 4; ++i) {
        int chunk = i * 256 + wid * 64 + lane;
        int row = chunk >> 4, cc = chunk & 15;
        int ccs = (cc & ~7) | ((cc ^ row) & 7);
        gld_lds16(A + (size_t)(arow0 + row) * 128 + ccs * 8, &lA[(i * 256 + wid * 64) * 8]);
    }
    auto stageB = [&](int t, int buf) {
        int q = t >> 1, kt = t & 1;
#pragma unroll
        for (int i = 0; i < 4; ++i) {
            int chunk = i * 256 + wid * 64 + lane;
            int row = chunk >> 3, cc = chunk & 7;
            int ccs = cc ^ (row & 7);
            gld_lds16(Bp + (size_t)(q * 128 + row) * 128 + kt * 64 + ccs * 8,
                      &lB[buf][(i * 256 + wid * 64) * 8]);
        }
    };
    stageB(0, 0);
    asm volatile("s_waitcnt vmcnt(0)" ::: "memory");
    __syncthreads();

    bf16x8 af[4];
#pragma unroll
    for (int ks = 0; ks < 4; ++ks) {
        int chunk = ks * 4 + lhi;
        int ccs = (chunk & ~7) | ((chunk ^ lrow) & 7);
        af[ks] = *(const bf16x8*)&lA[(size_t)(wid * 16 + lrow) * 128 + ccs * 8];
    }

    const int rowg = arow0 + wid * 16 + lrow;
    auto storeq = [&](int q, f32x4 (&aq)[8]) {
        if (rowg >= Mmax) return;
#pragma unroll
        for (int n2 = 0; n2 < 8; ++n2) {
            int colg = q * 128 + n2 * 16 + lhi * 4;
            if (colg >= 704) continue;
            float4 bv = *(const float4*)&bias[colg];
            float v0 = aq[n2][0] + bv.x, v1 = aq[n2][1] + bv.y;
            float v2 = aq[n2][2] + bv.z, v3 = aq[n2][3] + bv.w;
            if (colg < 640) {
                ushort4 o;
                o.x = f2b(v0); o.y = f2b(v1); o.z = f2b(v2); o.w = f2b(v3);
                if (colg < 256)
                    *(ushort4*)&qb[(size_t)rowg * 256 + colg] = o;
                else if (colg < 512)
                    *(ushort4*)&kb[(size_t)rowg * 256 + (colg - 256)] = o;
                else
                    *(ushort4*)&vcb[(size_t)rowg * 128 + (colg - 512)] = o;
            } else {
                float4 o; o.x = v0; o.y = v1; o.z = v2; o.w = v3;
                *(float4*)&outf[(size_t)rowg * 64 + (colg - 640)] = o;
            }
        }
    };

    f32x4 acc[3][8] = {};
#pragma unroll
    for (int t = 0; t < 12; ++t) {
        const int qq = (t >> 1) % 3;
        if (t + 1 < 12) stageB(t + 1, (t + 1) & 1);
        const u16* lBc = lB[t & 1];
#pragma unroll
        for (int ks = 0; ks < 2; ++ks) {
            bf16x8 bf[8];
#pragma unroll
            for (int n2 = 0; n2 < 8; ++n2) {
                int chunk = (ks * 4 + lhi) ^ (lrow & 7);
                bf[n2] = *(const bf16x8*)&lBc[(size_t)(n2 * 16 + lrow) * 64 + chunk * 8];
            }
#pragma unroll
            for (int n2 = 0; n2 < 8; ++n2)
                acc[qq][n2] = __builtin_amdgcn_mfma_f32_16x16x32_bf16(
                    bf[n2], af[(t & 1) * 2 + ks], acc[qq][n2], 0, 0, 0);
        }
        asm volatile("s_waitcnt vmcnt(0)" ::: "memory");
        __syncthreads();
        if (t == 5) {
            storeq(0, acc[0]); storeq(1, acc[1]); storeq(2, acc[2]);
#pragma unroll
            for (int q2 = 0; q2 < 3; ++q2)
#pragma unroll
                for (int n2 = 0; n2 < 8; ++n2)
                    acc[q2][n2] = (f32x4){0.f, 0.f, 0.f, 0.f};
        }
    }
    storeq(3, acc[0]); storeq(4, acc[1]); storeq(5, acc[2]);
}

// ---------------- CSR attention: one wave per dst, no atomics ----------------
__global__ __launch_bounds__(256) void k_attn(
    const u16* __restrict__ qB, const u16* __restrict__ kB, const u16* __restrict__ vcB,
    const int* __restrict__ startA, const int* __restrict__ deg,
    const int* __restrict__ esrc, float* __restrict__ out) {
    int wid = threadIdx.x >> 6, lane = threadIdx.x & 63;
    int dst = blockIdx.x * 4 + wid;
    if (dst >= N_NODES) return;
    int d = deg[dst];
    if (d == 0) return;
    int st = startA[dst];

    ushort4 qv = *(const ushort4*)&qB[(size_t)dst * 256 + lane * 4];
    float q0 = b2f(qv.x), q1 = b2f(qv.y), q2 = b2f(qv.z), q3 = b2f(qv.w);
    const float inv = 0.08838834764831845f;  // 1/sqrt(128)

    float s0 = 0.f, s1 = 0.f, accA = 0.f, accB = 0.f;
    for (int p = st; p < st + d; ++p) {
        int src = esrc[p];
        ushort4 kv = *(const ushort4*)&kB[(size_t)src * 256 + lane * 4];
        float pp = q0 * b2f(kv.x) + q1 * b2f(kv.y) + q2 * b2f(kv.z) + q3 * b2f(kv.w);
        pp += __shfl_xor(pp, 1);
        pp += __shfl_xor(pp, 2);
        pp += __shfl_xor(pp, 4);
        pp += __shfl_xor(pp, 8);
        pp += __shfl_xor(pp, 16);
        float e = expf(pp * inv);
        float eo = __shfl_xor(e, 32);
        float e0 = (lane < 32) ? e : eo;
        float e1 = (lane < 32) ? eo : e;
        s0 += e0; s1 += e1;
        float v0 = b2f(vcB[(size_t)src * 128 + lane]);
        float v1 = b2f(vcB[(size_t)src * 128 + 64 + lane]);
        accA += e0 * v0;
        accB += e1 * v1;
    }
    float* op = out + (size_t)dst * 64 + lane;
    *op += accA / s0 + accB / s1;
}

extern "C" void kernel_launch(void* const* d_in, const int* in_sizes, int n_in,
                              void* d_out, int out_size, void* d_ws, size_t ws_size,
                              hipStream_t stream) {
    const float* memory = (const float*)d_in[0];
    const float* W1 = (const float*)d_in[1];  const float* b1 = (const float*)d_in[2];
    const float* W2 = (const float*)d_in[3];  const float* b2 = (const float*)d_in[4];
    const float* Wih = (const float*)d_in[5]; const float* Whh = (const float*)d_in[6];
    const float* bih = (const float*)d_in[7]; const float* bhh = (const float*)d_in[8];
    const float* Wq = (const float*)d_in[9];  const float* bq = (const float*)d_in[10];
    const float* Wk = (const float*)d_in[11]; const float* bk = (const float*)d_in[12];
    const float* Wv = (const float*)d_in[13]; const float* bv = (const float*)d_in[14];
    const float* Ws = (const float*)d_in[15]; const float* bs = (const float*)d_in[16];
    const float* Wc = (const float*)d_in[17]; const float* bc = (const float*)d_in[18];
    const float* eattr = (const float*)d_in[19];
    const int* ei = (const int*)d_in[21];
    float* out = (float*)d_out;

    char* ws = (char*)d_ws;
    size_t off = 0;
    auto alloc = [&](size_t bytes) -> char* {
        char* p = ws + off;
        off = (off + bytes + 255) & ~(size_t)255;
        return p;
    };
    u16* xb = (u16*)alloc((size_t)NPAD * 128 * 2);
    u16* qb = (u16*)alloc((size_t)NPAD * 256 * 2);
    u16* kb = (u16*)alloc((size_t)NPAD * 256 * 2);
    u16* vcb = (u16*)alloc((size_t)NPAD * 128 * 2);
    int* winner = (int*)alloc((size_t)N_NODES * 4);
    int* wnode = (int*)alloc((size_t)N_NODES * 4);
    int* wedge = (int*)alloc((size_t)N_NODES * 4);
    int* wsrc = (int*)alloc((size_t)N_NODES * 4);
    int* deg = (int*)alloc((size_t)N_NODES * 4);
    int* startA = (int*)alloc((size_t)N_NODES * 4);
    int* cursor = (int*)alloc((size_t)N_NODES * 4);
    int* esrc = (int*)alloc((size_t)E_EDGES * 4);
    int* counters = (int*)alloc(256);
    u16* W1p = (u16*)alloc(49152 * 2);
    u16* Wcat2p = (u16*)alloc(131072 * 2);
    u16* Wprojp = (u16*)alloc(98304 * 2);
    float* bias2 = (float*)alloc(512 * 4);
    float* bproj = (float*)alloc(768 * 4);
    (void)ws_size; (void)in_sizes; (void)n_in; (void)out_size;

    int* wcount = counters;  // counters[0]=wcount, counters[1]=etot

    hipLaunchKernelGGL(k_init, dim3(391), dim3(256), 0, stream, winner, deg, counters);
    hipLaunchKernelGGL(k_edges, dim3(1563), dim3(256), 0, stream, ei, winner, deg);
    hipLaunchKernelGGL(k_nodes, dim3(391), dim3(256), 0, stream,
                       winner, deg, ei, wnode, wedge, wsrc, counters, startA, cursor);
    hipLaunchKernelGGL(k_fill, dim3(1563), dim3(256), 0, stream, ei, cursor, esrc);
    hipLaunchKernelGGL(k_pack, dim3(579), dim3(256), 0, stream,
                       W1, Wq, Wk, Wv, Ws, Wc, bq, bk, bv, bs, bc, W1p, Wprojp, bproj);
    hipLaunchKernelGGL(k_fold, dim3(512), dim3(128), 0, stream,
                       W2, Wih, Whh, bih, bhh, b2, Wcat2p, bias2);
    hipLaunchKernelGGL(k_xinit, dim3(12500), dim3(256), 0, stream, memory, winner, xb);
    // fused gather + MLP + GRU for winner rows
    hipLaunchKernelGGL(k_mg, dim3(1564), dim3(256), 0, stream,
                       memory, eattr, wnode, wedge, wsrc, wcount,
                       W1p, b1, Wcat2p, bias2, xb);
    // proj: [q|k|vc|skip] = xb @ Wproj + bproj  (skip -> out, f32)
    hipLaunchKernelGGL(k_proj, dim3(1564), dim3(256), 0, stream,
                       xb, Wprojp, bproj, N_NODES, qb, kb, vcb, out);
    // CSR attention: out[dst] += sum(alpha * vc[src]) per head, no atomics
    hipLaunchKernelGGL(k_attn, dim3(25000), dim3(256), 0, stream,
                       qb, kb, vcb, startA, deg, esrc, out);
}

// Round 11
// 478.194 us; speedup vs baseline: 1.5478x; 1.5473x over previous
//
#include <hip/hip_runtime.h>
#include <hip/hip_bf16.h>

#define N_NODES 100000
#define E_EDGES 400000
#define NPAD 100096   // 1564 * 64

typedef unsigned short u16;
typedef __attribute__((ext_vector_type(4))) float f32x4;
typedef __attribute__((ext_vector_type(8))) short bf16x8;

__device__ inline u16 f2b(float v) {
    __hip_bfloat16 h = __float2bfloat16(v);
    return *reinterpret_cast<u16*>(&h);
}
__device__ inline float b2f(u16 u) { return __uint_as_float(((unsigned)u) << 16); }

__device__ inline void gld_lds16(const u16* g, u16* l) {
    __builtin_amdgcn_global_load_lds(
        (const __attribute__((address_space(1))) unsigned*)g,
        (__attribute__((address_space(3))) unsigned*)l, 16, 0, 0);
}

// ---------------- fold W2/b2 into Wcat: Wcat2p[512][256] bf16, bias2[512] f32 ----------
__global__ __launch_bounds__(128) void k_fold(
    const float* __restrict__ W2, const float* __restrict__ Wih,
    const float* __restrict__ Whh, const float* __restrict__ bih,
    const float* __restrict__ bhh, const float* __restrict__ b2,
    u16* __restrict__ Wcat2p, float* __restrict__ bias2) {
    int c = blockIdx.x, t = threadIdx.x;
    __shared__ float wrow[128];
    __shared__ float red[128];
    wrow[t] = (c < 384) ? Wih[c * 128 + t] : 0.f;
    __syncthreads();
    float a = 0.f;
    for (int m = 0; m < 128; ++m) a += W2[t * 128 + m] * wrow[m];
    Wcat2p[c * 256 + t] = f2b(a);
    float dv = (c < 256) ? Whh[c * 128 + t] : (c >= 384 ? Whh[(c - 128) * 128 + t] : 0.f);
    Wcat2p[c * 256 + 128 + t] = f2b(dv);
    red[t] = b2[t] * wrow[t];
    __syncthreads();
    for (int o = 64; o; o >>= 1) { if (t < o) red[t] += red[t + o]; __syncthreads(); }
    if (t == 0) {
        float b = (c < 256) ? bih[c] + bhh[c] + red[0]
                : (c < 384 ? bih[c] + red[0] : bhh[c - 128]);
        bias2[c] = b;
    }
}

// ---------------- pack W1 + proj weights (Wc-fold computed inline) ----------------
__global__ __launch_bounds__(256) void k_pack(
    const float* __restrict__ W1,
    const float* __restrict__ Wq, const float* __restrict__ Wk,
    const float* __restrict__ Wv, const float* __restrict__ Ws,
    const float* __restrict__ Wc,
    const float* __restrict__ bq, const float* __restrict__ bk,
    const float* __restrict__ bv, const float* __restrict__ bs,
    const float* __restrict__ bc,
    u16* __restrict__ W1p, u16* __restrict__ Wprojp, float* __restrict__ bproj) {
    int i = blockIdx.x * 256 + threadIdx.x;
    if (i < 49152) { int n = i / 384, k2 = i % 384; W1p[i] = f2b(W1[k2 * 128 + n]); return; }
    i -= 49152;
    if (i < 98304) {
        int n = i / 128, k2 = i % 128; float v;
        if (n < 256)      v = Wq[k2 * 256 + n];
        else if (n < 512) v = Wk[k2 * 256 + (n - 256)];
        else if (n < 640) {
            int t = n - 512, h = t >> 6, o = t & 63;
            float a = 0.f;
            for (int c = 0; c < 128; ++c) a += Wv[k2 * 256 + h * 128 + c] * Wc[(h * 128 + c) * 64 + o];
            v = a;
        } else if (n < 704) {
            int o = n - 640;
            float a = 0.f;
            for (int j = 0; j < 256; ++j) a += Ws[k2 * 256 + j] * Wc[j * 64 + o];
            v = a;
        } else v = 0.f;
        Wprojp[i] = f2b(v); return;
    }
    i -= 98304;
    if (i < 768) {
        float v;
        if (i < 256)      v = bq[i];
        else if (i < 512) v = bk[i - 256];
        else if (i < 640) {
            int t = i - 512, h = t >> 6, o = t & 63;
            float a = 0.f;
            for (int c = 0; c < 128; ++c) a += bv[h * 128 + c] * Wc[(h * 128 + c) * 64 + o];
            v = a;
        } else if (i < 704) {
            int o = i - 640;
            float a = bc[o];
            for (int j = 0; j < 256; ++j) a += bs[j] * Wc[j * 64 + o];
            v = a;
        } else v = 0.f;
        bproj[i] = v;
    }
}

// ---------------- init ----------------
__global__ void k_init(int* __restrict__ winner, int* __restrict__ deg,
                       int* __restrict__ counters) {
    int n = blockIdx.x * 256 + threadIdx.x;
    if (n == 0) { counters[0] = 0; counters[1] = 0; }  // wcount, etot
    if (n < N_NODES) { winner[n] = -1; deg[n] = 0; }
}

// ---------------- edge pass: winner (max edge idx) + degree histogram ----------------
__global__ void k_edges(const int* __restrict__ ei, int* __restrict__ winner,
                        int* __restrict__ deg) {
    int e = blockIdx.x * 256 + threadIdx.x;
    if (e < E_EDGES) {
        int dst = ei[E_EDGES + e];
        atomicMax(&winner[dst], e);
        atomicAdd(&deg[dst], 1);
    }
}

// -------- node pass: compact winners (node, edge, src triples) + CSR alloc --------
__global__ void k_nodes(const int* __restrict__ winner, const int* __restrict__ deg,
                        const int* __restrict__ ei,
                        int* __restrict__ wnode, int* __restrict__ wedge,
                        int* __restrict__ wsrc, int* __restrict__ counters,
                        int* __restrict__ startA, int* __restrict__ cursor) {
    int n = blockIdx.x * 256 + threadIdx.x;
    if (n >= N_NODES) return;
    int we = winner[n];
    if (we >= 0) {
        int i = atomicAdd(&counters[0], 1);
        wnode[i] = n;
        wedge[i] = we;
        wsrc[i] = ei[we];
    }
    int d = deg[n];
    int st = d ? atomicAdd(&counters[1], d) : 0;
    startA[n] = st;
    cursor[n] = st;
}

// ---------------- fill CSR: segment holds src node of each in-edge ----------------
__global__ void k_fill(const int* __restrict__ ei, int* __restrict__ cursor,
                       int* __restrict__ esrc) {
    int e = blockIdx.x * 256 + threadIdx.x;
    if (e < E_EDGES) {
        int dst = ei[E_EDGES + e];
        int pos = atomicAdd(&cursor[dst], 1);
        esrc[pos] = ei[e];
    }
}

// ---------------- x init (bf16 copy of memory; winner rows overwritten by k_mg) -------
__global__ void k_xinit(const float* __restrict__ mem, const int* __restrict__ winner,
                        u16* __restrict__ x) {
    size_t idx = ((size_t)blockIdx.x * 256 + threadIdx.x) * 4;
    if (idx >= (size_t)N_NODES * 128) return;
    if (winner[idx >> 7] >= 0) return;   // GRU will write this row
    float4 v = *(const float4*)(mem + idx);
    ushort4 o;
    o.x = f2b(v.x); o.y = f2b(v.y); o.z = f2b(v.z); o.w = f2b(v.w);
    *(ushort4*)(x + idx) = o;
}

// ========== fused gather + message-MLP + GRU for winner rows -> xb ==========
// r6-proven skeleton. r7-r10 diagnosis: the 16-tile GEMM2 loop with embedded
// sigmoid block failed to unroll -> acc2[qq]/rz runtime-indexed -> scratch
// (rule #20; VGPR 88 + 600MB scratch). Fix: GEMM2 as TWO 8-tile passes with
// NAMED accumulators accP/accQ (reused), sigmoid/rz between passes, 2-way
// static af selects. Every array index is compile-time even if a loop rolls.
__global__ __launch_bounds__(256, 1) void k_mg(
    const float* __restrict__ mem, const float* __restrict__ eattr,
    const int* __restrict__ wnode, const int* __restrict__ wedge,
    const int* __restrict__ wsrc, const int* __restrict__ Mp,
    const u16* __restrict__ W1p, const float* __restrict__ b1,
    const u16* __restrict__ Wcat2p, const float* __restrict__ bias2,
    u16* __restrict__ xb) {
    __shared__ u16 lB[2][128 * 64];
    __shared__ u16 h1l[64][136];   // padded rows -> 2-way-free banking

    const int tid = threadIdx.x;
    const int wid = tid >> 6, lane = tid & 63;
    const int lrow = lane & 15, lhi = lane >> 4;
    const int M = *Mp;
    const int arow0 = blockIdx.x * 64;
    if (arow0 >= M) return;

    const int rowg = arow0 + wid * 16 + lrow;
    const int rowc = min(rowg, M - 1);
    const int node = wnode[rowc];
    const int we = wedge[rowc];
    const int src = wsrc[rowc];

    // gather A fragments [src|dst|eattr] straight to registers (r6 exact)
    bf16x8 af[12];
#pragma unroll
    for (int ks = 0; ks < 12; ++ks) {
        int c = ks * 4 + lhi;
        const float* p;
        if (c < 16)      p = mem + (size_t)src * 128 + c * 8;
        else if (c < 32) p = mem + (size_t)node * 128 + (c - 16) * 8;
        else             p = eattr + (size_t)we * 128 + (c - 32) * 8;
        float4 v0 = *(const float4*)p;
        float4 v1 = *(const float4*)(p + 4);
        bf16x8 a;
        a[0] = (short)f2b(v0.x); a[1] = (short)f2b(v0.y);
        a[2] = (short)f2b(v0.z); a[3] = (short)f2b(v0.w);
        a[4] = (short)f2b(v1.x); a[5] = (short)f2b(v1.y);
        a[6] = (short)f2b(v1.z); a[7] = (short)f2b(v1.w);
        af[ks] = a;
    }

    auto stB = [&](const u16* Bp, int K, int rowoff, int kt, int buf) {
#pragma unroll
        for (int i = 0; i < 4; ++i) {
            int chunk = i * 256 + wid * 64 + lane;
            int row = chunk >> 3, cc = chunk & 7;
            int ccs = cc ^ (row & 7);
            gld_lds16(Bp + (size_t)(rowoff + row) * K + kt * 64 + ccs * 8,
                      &lB[buf][(i * 256 + wid * 64) * 8]);
        }
    };
    stB(W1p, 384, 0, 0, 0);
    asm volatile("s_waitcnt vmcnt(0)" ::: "memory");
    __syncthreads();

    // ---- GEMM1: h1 = relu([src|dst|eattr] @ W1 + b1), K=384, N=128 (r6 exact) ----
    f32x4 acc1[8] = {};
#pragma unroll
    for (int kt = 0; kt < 6; ++kt) {
        if (kt + 1 < 6) stB(W1p, 384, 0, kt + 1, (kt + 1) & 1);
        const u16* lBc = lB[kt & 1];
#pragma unroll
        for (int ks = 0; ks < 2; ++ks) {
            bf16x8 bf[8];
#pragma unroll
            for (int n2 = 0; n2 < 8; ++n2) {
                int chunk = (ks * 4 + lhi) ^ (lrow & 7);
                bf[n2] = *(const bf16x8*)&lBc[(size_t)(n2 * 16 + lrow) * 64 + chunk * 8];
            }
#pragma unroll
            for (int n2 = 0; n2 < 8; ++n2)
                acc1[n2] = __builtin_amdgcn_mfma_f32_16x16x32_bf16(
                    bf[n2], af[kt * 2 + ks], acc1[n2], 0, 0, 0);
        }
        asm volatile("s_waitcnt vmcnt(0)" ::: "memory");
        __syncthreads();
    }

    // stage GEMM2 tile 0 while h1 goes to LDS
    stB(Wcat2p, 256, 0, 0, 0);
    {
        const int rl = wid * 16 + lrow;
#pragma unroll
        for (int n2 = 0; n2 < 8; ++n2) {
            int col = n2 * 16 + lhi * 4;
            float4 bv = *(const float4*)&b1[col];
            ushort4 o;
            o.x = f2b(fmaxf(acc1[n2][0] + bv.x, 0.f));
            o.y = f2b(fmaxf(acc1[n2][1] + bv.y, 0.f));
            o.z = f2b(fmaxf(acc1[n2][2] + bv.z, 0.f));
            o.w = f2b(fmaxf(acc1[n2][3] + bv.w, 0.f));
            *(ushort4*)&h1l[rl][col] = o;
        }
    }
    asm volatile("s_waitcnt vmcnt(0)" ::: "memory");
    __syncthreads();

    // A-fragments for GEMM2: k<128 from h1 (LDS), k>=128 = dst half = af[4..7]
    bf16x8 af2[4];
#pragma unroll
    for (int ks = 0; ks < 4; ++ks)
        af2[ks] = *(const bf16x8*)&h1l[wid * 16 + lrow][ks * 32 + lhi * 8];

    // ---- GEMM2 PASS A: quads 0,1 (R,Z) = global tiles 0..7 ----
    f32x4 accP[8] = {}, accQ[8] = {};
#pragma unroll
    for (int tt = 0; tt < 8; ++tt) {
        {
            int g = tt + 1;   // next global tile 1..8 (tile 8 = quad2 kt0, buf 0)
            stB(Wcat2p, 256, (g >> 2) * 128, g & 3, g & 1);
        }
        const u16* lBc = lB[tt & 1];
#pragma unroll
        for (int ks = 0; ks < 2; ++ks) {
            const int kk = (tt & 3) * 2 + ks;
            bf16x8 a = (kk < 4) ? af2[kk] : af[kk];
            bf16x8 bf[8];
#pragma unroll
            for (int n2 = 0; n2 < 8; ++n2) {
                int chunk = (ks * 4 + lhi) ^ (lrow & 7);
                bf[n2] = *(const bf16x8*)&lBc[(size_t)(n2 * 16 + lrow) * 64 + chunk * 8];
            }
            if (tt < 4) {
#pragma unroll
                for (int n2 = 0; n2 < 8; ++n2)
                    accP[n2] = __builtin_amdgcn_mfma_f32_16x16x32_bf16(
                        bf[n2], a, accP[n2], 0, 0, 0);
            } else {
#pragma unroll
                for (int n2 = 0; n2 < 8; ++n2)
                    accQ[n2] = __builtin_amdgcn_mfma_f32_16x16x32_bf16(
                        bf[n2], a, accQ[n2], 0, 0, 0);
            }
        }
        asm volatile("s_waitcnt vmcnt(0)" ::: "memory");
        __syncthreads();
    }

    // ---- between passes: r = sigmoid(R), z = sigmoid(Z) -> packed bf16 pairs ----
    unsigned rz[32];
#pragma unroll
    for (int n2 = 0; n2 < 8; ++n2) {
        int col = n2 * 16 + lhi * 4;
        float4 br = *(const float4*)&bias2[col];
        float4 bz = *(const float4*)&bias2[128 + col];
#pragma unroll
        for (int j = 0; j < 4; ++j) {
            float bR = (j == 0) ? br.x : (j == 1) ? br.y : (j == 2) ? br.z : br.w;
            float bZ = (j == 0) ? bz.x : (j == 1) ? bz.y : (j == 2) ? bz.z : bz.w;
            float r = 1.f / (1.f + expf(-(accP[n2][j] + bR)));
            float z = 1.f / (1.f + expf(-(accQ[n2][j] + bZ)));
            rz[n2 * 4 + j] = (unsigned)f2b(r) | ((unsigned)f2b(z) << 16);
        }
        accP[n2] = (f32x4){0.f, 0.f, 0.f, 0.f};
        accQ[n2] = (f32x4){0.f, 0.f, 0.f, 0.f};
    }

    // ---- GEMM2 PASS B: quads 2,3 (IN,HN) = global tiles 8..15 ----
#pragma unroll
    for (int tt = 0; tt < 8; ++tt) {
        if (tt < 7) {
            int g = 9 + tt;   // next global tile 9..15
            stB(Wcat2p, 256, (g >> 2) * 128, g & 3, g & 1);
        }
        const u16* lBc = lB[tt & 1];   // global tile 8+tt, (8+tt)&1 == tt&1
#pragma unroll
        for (int ks = 0; ks < 2; ++ks) {
            const int kk = (tt & 3) * 2 + ks;
            bf16x8 a = (kk < 4) ? af2[kk] : af[kk];
            bf16x8 bf[8];
#pragma unroll
            for (int n2 = 0; n2 < 8; ++n2) {
                int chunk = (ks * 4 + lhi) ^ (lrow & 7);
                bf[n2] = *(const bf16x8*)&lBc[(size_t)(n2 * 16 + lrow) * 64 + chunk * 8];
            }
            if (tt < 4) {
#pragma unroll
                for (int n2 = 0; n2 < 8; ++n2)
                    accP[n2] = __builtin_amdgcn_mfma_f32_16x16x32_bf16(
                        bf[n2], a, accP[n2], 0, 0, 0);
            } else {
#pragma unroll
                for (int n2 = 0; n2 < 8; ++n2)
                    accQ[n2] = __builtin_amdgcn_mfma_f32_16x16x32_bf16(
                        bf[n2], a, accQ[n2], 0, 0, 0);
            }
        }
        asm volatile("s_waitcnt vmcnt(0)" ::: "memory");
        __syncthreads();
    }

    // ---- GRU epilogue -> xb[node] (accP=IN, accQ=HN) ----
    if (rowg >= M) return;
#pragma unroll
    for (int n2 = 0; n2 < 8; ++n2) {
        int col = n2 * 16 + lhi * 4;
        float4 bn = *(const float4*)&bias2[256 + col];
        float4 bh = *(const float4*)&bias2[384 + col];
        float4 hv = *(const float4*)&mem[(size_t)node * 128 + col];
        ushort4 o;
#pragma unroll
        for (int j = 0; j < 4; ++j) {
            float bN = (j == 0) ? bn.x : (j == 1) ? bn.y : (j == 2) ? bn.z : bn.w;
            float bH = (j == 0) ? bh.x : (j == 1) ? bh.y : (j == 2) ? bh.z : bh.w;
            float hj = (j == 0) ? hv.x : (j == 1) ? hv.y : (j == 2) ? hv.z : hv.w;
            unsigned p = rz[n2 * 4 + j];
            float r = b2f((u16)(p & 0xffff));
            float z = b2f((u16)(p >> 16));
            float n = tanhf(accP[n2][j] + bN + r * (accQ[n2][j] + bH));
            u16 res = f2b((1.f - z) * n + z * hj);
            if (j == 0) o.x = res; else if (j == 1) o.y = res;
            else if (j == 2) o.z = res; else o.w = res;
        }
        *(ushort4*)&xb[(size_t)node * 128 + col] = o;
    }
}

// ================= proj GEMM: EXACT round-6-measured template (477µs run) ==========
template <int K, int NQUAD>
__global__ __launch_bounds__(256, 1) void k_proj(
    const u16* __restrict__ A, const u16* __restrict__ Bp,
    const float* __restrict__ bias, int Mmax,
    u16* __restrict__ qb, u16* __restrict__ kb, u16* __restrict__ vcb,
    float* __restrict__ outf) {
    constexpr int KT = K / 64;
    constexpr int NT = NQUAD * KT;
    constexpr int NKS = K / 32;
    constexpr int CPR = K / 8;
    __shared__ u16 lA[64 * K];
    __shared__ u16 lB[2][128 * 64];

    const int tid = threadIdx.x;
    const int wid = tid >> 6, lane = tid & 63;
    const int lrow = lane & 15, lhi = lane >> 4;
    const int arow0 = blockIdx.x * 64;

#pragma unroll
    for (int i = 0; i < (64 * CPR) / 256; ++i) {
        int chunk = i * 256 + wid * 64 + lane;
        int row = chunk / CPR, cc = chunk % CPR;
        int ccs = (cc & ~7) | ((cc ^ row) & 7);
        gld_lds16(A + (size_t)(arow0 + row) * K + ccs * 8, &lA[(i * 256 + wid * 64) * 8]);
    }
    auto stageB = [&](int t, int buf) {
        int q = t / KT, kt = t - q * KT;
#pragma unroll
        for (int i = 0; i < 4; ++i) {
            int chunk = i * 256 + wid * 64 + lane;
            int row = chunk >> 3, cc = chunk & 7;
            int ccs = cc ^ (row & 7);
            gld_lds16(Bp + (size_t)(q * 128 + row) * K + kt * 64 + ccs * 8,
                      &lB[buf][(i * 256 + wid * 64) * 8]);
        }
    };
    stageB(0, 0);
    asm volatile("s_waitcnt vmcnt(0)" ::: "memory");
    __syncthreads();

    bf16x8 af[NKS];
#pragma unroll
    for (int ks = 0; ks < NKS; ++ks) {
        int chunk = ks * 4 + lhi;
        int ccs = (chunk & ~7) | ((chunk ^ lrow) & 7);
        af[ks] = *(const bf16x8*)&lA[(size_t)(wid * 16 + lrow) * K + ccs * 8];
    }

    f32x4 acc[NQUAD][8] = {};
#pragma unroll
    for (int t = 0; t < NT; ++t) {
        const int q = t / KT, kt = t - q * KT;
        if (t + 1 < NT) stageB(t + 1, (t + 1) & 1);
        const u16* lBc = lB[t & 1];
#pragma unroll
        for (int ks = 0; ks < 2; ++ks) {
            bf16x8 bf[8];
#pragma unroll
            for (int n2 = 0; n2 < 8; ++n2) {
                int chunk = (ks * 4 + lhi) ^ (lrow & 7);
                bf[n2] = *(const bf16x8*)&lBc[(size_t)(n2 * 16 + lrow) * 64 + chunk * 8];
            }
#pragma unroll
            for (int n2 = 0; n2 < 8; ++n2)
                acc[q][n2] = __builtin_amdgcn_mfma_f32_16x16x32_bf16(
                    bf[n2], af[kt * 2 + ks], acc[q][n2], 0, 0, 0);
        }
        asm volatile("s_waitcnt vmcnt(0)" ::: "memory");
        __syncthreads();
    }

    const int rowg = arow0 + wid * 16 + lrow;
    if (rowg >= Mmax) return;

#pragma unroll
    for (int q = 0; q < NQUAD; ++q) {
#pragma unroll
        for (int n2 = 0; n2 < 8; ++n2) {
            int colg = q * 128 + n2 * 16 + lhi * 4;
            if (colg >= 704) continue;
            float4 bv = *(const float4*)&bias[colg];
            float v0 = acc[q][n2][0] + bv.x, v1 = acc[q][n2][1] + bv.y;
            float v2 = acc[q][n2][2] + bv.z, v3 = acc[q][n2][3] + bv.w;
            if (colg < 640) {
                ushort4 o;
                o.x = f2b(v0); o.y = f2b(v1); o.z = f2b(v2); o.w = f2b(v3);
                if (colg < 256)
                    *(ushort4*)&qb[(size_t)rowg * 256 + colg] = o;
                else if (colg < 512)
                    *(ushort4*)&kb[(size_t)rowg * 256 + (colg - 256)] = o;
                else
                    *(ushort4*)&vcb[(size_t)rowg * 128 + (colg - 512)] = o;
            } else {
                float4 o; o.x = v0; o.y = v1; o.z = v2; o.w = v3;
                *(float4*)&outf[(size_t)rowg * 64 + (colg - 640)] = o;
            }
        }
    }
}

// ---------------- CSR attention: one wave per dst, no atomics ----------------
__global__ __launch_bounds__(256) void k_attn(
    const u16* __restrict__ qB, const u16* __restrict__ kB, const u16* __restrict__ vcB,
    const int* __restrict__ startA, const int* __restrict__ deg,
    const int* __restrict__ esrc, float* __restrict__ out) {
    int wid = threadIdx.x >> 6, lane = threadIdx.x & 63;
    int dst = blockIdx.x * 4 + wid;
    if (dst >= N_NODES) return;
    int d = deg[dst];
    if (d == 0) return;
    int st = startA[dst];

    ushort4 qv = *(const ushort4*)&qB[(size_t)dst * 256 + lane * 4];
    float q0 = b2f(qv.x), q1 = b2f(qv.y), q2 = b2f(qv.z), q3 = b2f(qv.w);
    const float inv = 0.08838834764831845f;  // 1/sqrt(128)

    float s0 = 0.f, s1 = 0.f, accA = 0.f, accB = 0.f;
    for (int p = st; p < st + d; ++p) {
        int src = esrc[p];
        ushort4 kv = *(const ushort4*)&kB[(size_t)src * 256 + lane * 4];
        float pp = q0 * b2f(kv.x) + q1 * b2f(kv.y) + q2 * b2f(kv.z) + q3 * b2f(kv.w);
        pp += __shfl_xor(pp, 1);
        pp += __shfl_xor(pp, 2);
        pp += __shfl_xor(pp, 4);
        pp += __shfl_xor(pp, 8);
        pp += __shfl_xor(pp, 16);
        float e = expf(pp * inv);
        float eo = __shfl_xor(e, 32);
        float e0 = (lane < 32) ? e : eo;
        float e1 = (lane < 32) ? eo : e;
        s0 += e0; s1 += e1;
        float v0 = b2f(vcB[(size_t)src * 128 + lane]);
        float v1 = b2f(vcB[(size_t)src * 128 + 64 + lane]);
        accA += e0 * v0;
        accB += e1 * v1;
    }
    float* op = out + (size_t)dst * 64 + lane;
    *op += accA / s0 + accB / s1;
}

extern "C" void kernel_launch(void* const* d_in, const int* in_sizes, int n_in,
                              void* d_out, int out_size, void* d_ws, size_t ws_size,
                              hipStream_t stream) {
    const float* memory = (const float*)d_in[0];
    const float* W1 = (const float*)d_in[1];  const float* b1 = (const float*)d_in[2];
    const float* W2 = (const float*)d_in[3];  const float* b2 = (const float*)d_in[4];
    const float* Wih = (const float*)d_in[5]; const float* Whh = (const float*)d_in[6];
    const float* bih = (const float*)d_in[7]; const float* bhh = (const float*)d_in[8];
    const float* Wq = (const float*)d_in[9];  const float* bq = (const float*)d_in[10];
    const float* Wk = (const float*)d_in[11]; const float* bk = (const float*)d_in[12];
    const float* Wv = (const float*)d_in[13]; const float* bv = (const float*)d_in[14];
    const float* Ws = (const float*)d_in[15]; const float* bs = (const float*)d_in[16];
    const float* Wc = (const float*)d_in[17]; const float* bc = (const float*)d_in[18];
    const float* eattr = (const float*)d_in[19];
    const int* ei = (const int*)d_in[21];
    float* out = (float*)d_out;

    char* ws = (char*)d_ws;
    size_t off = 0;
    auto alloc = [&](size_t bytes) -> char* {
        char* p = ws + off;
        off = (off + bytes + 255) & ~(size_t)255;
        return p;
    };
    u16* xb = (u16*)alloc((size_t)NPAD * 128 * 2);
    u16* qb = (u16*)alloc((size_t)NPAD * 256 * 2);
    u16* kb = (u16*)alloc((size_t)NPAD * 256 * 2);
    u16* vcb = (u16*)alloc((size_t)NPAD * 128 * 2);
    int* winner = (int*)alloc((size_t)N_NODES * 4);
    int* wnode = (int*)alloc((size_t)N_NODES * 4);
    int* wedge = (int*)alloc((size_t)N_NODES * 4);
    int* wsrc = (int*)alloc((size_t)N_NODES * 4);
    int* deg = (int*)alloc((size_t)N_NODES * 4);
    int* startA = (int*)alloc((size_t)N_NODES * 4);
    int* cursor = (int*)alloc((size_t)N_NODES * 4);
    int* esrc = (int*)alloc((size_t)E_EDGES * 4);
    int* counters = (int*)alloc(256);
    u16* W1p = (u16*)alloc(49152 * 2);
    u16* Wcat2p = (u16*)alloc(131072 * 2);
    u16* Wprojp = (u16*)alloc(98304 * 2);
    float* bias2 = (float*)alloc(512 * 4);
    float* bproj = (float*)alloc(768 * 4);
    (void)ws_size; (void)in_sizes; (void)n_in; (void)out_size;

    int* wcount = counters;  // counters[0]=wcount, counters[1]=etot

    hipLaunchKernelGGL(k_init, dim3(391), dim3(256), 0, stream, winner, deg, counters);
    hipLaunchKernelGGL(k_edges, dim3(1563), dim3(256), 0, stream, ei, winner, deg);
    hipLaunchKernelGGL(k_nodes, dim3(391), dim3(256), 0, stream,
                       winner, deg, ei, wnode, wedge, wsrc, counters, startA, cursor);
    hipLaunchKernelGGL(k_fill, dim3(1563), dim3(256), 0, stream, ei, cursor, esrc);
    hipLaunchKernelGGL(k_pack, dim3(579), dim3(256), 0, stream,
                       W1, Wq, Wk, Wv, Ws, Wc, bq, bk, bv, bs, bc, W1p, Wprojp, bproj);
    hipLaunchKernelGGL(k_fold, dim3(512), dim3(128), 0, stream,
                       W2, Wih, Whh, bih, bhh, b2, Wcat2p, bias2);
    hipLaunchKernelGGL(k_xinit, dim3(12500), dim3(256), 0, stream, memory, winner, xb);
    // fused gather + MLP + GRU for winner rows
    hipLaunchKernelGGL(k_mg, dim3(1564), dim3(256), 0, stream,
                       memory, eattr, wnode, wedge, wsrc, wcount,
                       W1p, b1, Wcat2p, bias2, xb);
    // proj: [q|k|vc|skip] = xb @ Wproj + bproj  (skip -> out, f32)
    hipLaunchKernelGGL((k_proj<128, 6>), dim3(1564), dim3(256), 0, stream,
                       xb, Wprojp, bproj, N_NODES, qb, kb, vcb, out);
    // CSR attention: out[dst] += sum(alpha * vc[src]) per head, no atomics
    hipLaunchKernelGGL(k_attn, dim3(25000), dim3(256), 0, stream,
                       qb, kb, vcb, startA, deg, esrc, out);
}

// Round 12
// 440.142 us; speedup vs baseline: 1.6816x; 1.0865x over previous
//
#include <hip/hip_runtime.h>
#include <hip/hip_bf16.h>

#define N_NODES 100000
#define E_EDGES 400000
#define NPAD 100096   // 1564 * 64

typedef unsigned short u16;
typedef __attribute__((ext_vector_type(4))) float f32x4;
typedef __attribute__((ext_vector_type(8))) short bf16x8;

__device__ inline u16 f2b(float v) {
    __hip_bfloat16 h = __float2bfloat16(v);
    return *reinterpret_cast<u16*>(&h);
}
__device__ inline float b2f(u16 u) { return __uint_as_float(((unsigned)u) << 16); }

__device__ inline void gld_lds16(const u16* g, u16* l) {
    __builtin_amdgcn_global_load_lds(
        (const __attribute__((address_space(1))) unsigned*)g,
        (__attribute__((address_space(3))) unsigned*)l, 16, 0, 0);
}

// ---------------- fold W2/b2 into Wcat: Wcat2p[512][256] bf16, bias2[512] f32 ----------
__global__ __launch_bounds__(128) void k_fold(
    const float* __restrict__ W2, const float* __restrict__ Wih,
    const float* __restrict__ Whh, const float* __restrict__ bih,
    const float* __restrict__ bhh, const float* __restrict__ b2,
    u16* __restrict__ Wcat2p, float* __restrict__ bias2) {
    int c = blockIdx.x, t = threadIdx.x;
    __shared__ float wrow[128];
    __shared__ float red[128];
    wrow[t] = (c < 384) ? Wih[c * 128 + t] : 0.f;
    __syncthreads();
    float a = 0.f;
    for (int m = 0; m < 128; ++m) a += W2[t * 128 + m] * wrow[m];
    Wcat2p[c * 256 + t] = f2b(a);
    float dv = (c < 256) ? Whh[c * 128 + t] : (c >= 384 ? Whh[(c - 128) * 128 + t] : 0.f);
    Wcat2p[c * 256 + 128 + t] = f2b(dv);
    red[t] = b2[t] * wrow[t];
    __syncthreads();
    for (int o = 64; o; o >>= 1) { if (t < o) red[t] += red[t + o]; __syncthreads(); }
    if (t == 0) {
        float b = (c < 256) ? bih[c] + bhh[c] + red[0]
                : (c < 384 ? bih[c] + red[0] : bhh[c - 128]);
        bias2[c] = b;
    }
}

// ---------------- pack W1 + proj weights (Wc-fold computed inline) ----------------
__global__ __launch_bounds__(256) void k_pack(
    const float* __restrict__ W1,
    const float* __restrict__ Wq, const float* __restrict__ Wk,
    const float* __restrict__ Wv, const float* __restrict__ Ws,
    const float* __restrict__ Wc,
    const float* __restrict__ bq, const float* __restrict__ bk,
    const float* __restrict__ bv, const float* __restrict__ bs,
    const float* __restrict__ bc,
    u16* __restrict__ W1p, u16* __restrict__ Wprojp, float* __restrict__ bproj) {
    int i = blockIdx.x * 256 + threadIdx.x;
    if (i < 49152) { int n = i / 384, k2 = i % 384; W1p[i] = f2b(W1[k2 * 128 + n]); return; }
    i -= 49152;
    if (i < 98304) {
        int n = i / 128, k2 = i % 128; float v;
        if (n < 256)      v = Wq[k2 * 256 + n];
        else if (n < 512) v = Wk[k2 * 256 + (n - 256)];
        else if (n < 640) {
            int t = n - 512, h = t >> 6, o = t & 63;
            float a = 0.f;
            for (int c = 0; c < 128; ++c) a += Wv[k2 * 256 + h * 128 + c] * Wc[(h * 128 + c) * 64 + o];
            v = a;
        } else if (n < 704) {
            int o = n - 640;
            float a = 0.f;
            for (int j = 0; j < 256; ++j) a += Ws[k2 * 256 + j] * Wc[j * 64 + o];
            v = a;
        } else v = 0.f;
        Wprojp[i] = f2b(v); return;
    }
    i -= 98304;
    if (i < 768) {
        float v;
        if (i < 256)      v = bq[i];
        else if (i < 512) v = bk[i - 256];
        else if (i < 640) {
            int t = i - 512, h = t >> 6, o = t & 63;
            float a = 0.f;
            for (int c = 0; c < 128; ++c) a += bv[h * 128 + c] * Wc[(h * 128 + c) * 64 + o];
            v = a;
        } else if (i < 704) {
            int o = i - 640;
            float a = bc[o];
            for (int j = 0; j < 256; ++j) a += bs[j] * Wc[j * 64 + o];
            v = a;
        } else v = 0.f;
        bproj[i] = v;
    }
}

// ---------------- init ----------------
__global__ void k_init(int* __restrict__ winner, int* __restrict__ deg,
                       int* __restrict__ counters) {
    int n = blockIdx.x * 256 + threadIdx.x;
    if (n == 0) { counters[0] = 0; counters[1] = 0; }  // wcount, etot
    if (n < N_NODES) { winner[n] = -1; deg[n] = 0; }
}

// ---------------- edge pass: winner (max edge idx) + degree histogram ----------------
__global__ void k_edges(const int* __restrict__ ei, int* __restrict__ winner,
                        int* __restrict__ deg) {
    int e = blockIdx.x * 256 + threadIdx.x;
    if (e < E_EDGES) {
        int dst = ei[E_EDGES + e];
        atomicMax(&winner[dst], e);
        atomicAdd(&deg[dst], 1);
    }
}

// -------- node pass: compact winners (node, edge, src triples) + CSR alloc --------
__global__ void k_nodes(const int* __restrict__ winner, const int* __restrict__ deg,
                        const int* __restrict__ ei,
                        int* __restrict__ wnode, int* __restrict__ wedge,
                        int* __restrict__ wsrc, int* __restrict__ counters,
                        int* __restrict__ startA, int* __restrict__ cursor) {
    int n = blockIdx.x * 256 + threadIdx.x;
    if (n >= N_NODES) return;
    int we = winner[n];
    if (we >= 0) {
        int i = atomicAdd(&counters[0], 1);
        wnode[i] = n;
        wedge[i] = we;
        wsrc[i] = ei[we];
    }
    int d = deg[n];
    int st = d ? atomicAdd(&counters[1], d) : 0;
    startA[n] = st;
    cursor[n] = st;
}

// ---------------- fill CSR: segment holds src node of each in-edge ----------------
__global__ void k_fill(const int* __restrict__ ei, int* __restrict__ cursor,
                       int* __restrict__ esrc) {
    int e = blockIdx.x * 256 + threadIdx.x;
    if (e < E_EDGES) {
        int dst = ei[E_EDGES + e];
        int pos = atomicAdd(&cursor[dst], 1);
        esrc[pos] = ei[e];
    }
}

// ---------------- x init (bf16 copy of memory; winner rows overwritten by k_mg) -------
__global__ void k_xinit(const float* __restrict__ mem, const int* __restrict__ winner,
                        u16* __restrict__ x) {
    size_t idx = ((size_t)blockIdx.x * 256 + threadIdx.x) * 4;
    if (idx >= (size_t)N_NODES * 128) return;
    if (winner[idx >> 7] >= 0) return;   // GRU will write this row
    float4 v = *(const float4*)(mem + idx);
    ushort4 o;
    o.x = f2b(v.x); o.y = f2b(v.y); o.z = f2b(v.z); o.w = f2b(v.w);
    *(ushort4*)(x + idx) = o;
}

// ========== fused gather + message-MLP + GRU for winner rows -> xb ==========
// r11's no-spill structure (named accs, static indices, 3 unrolled loops)
// + T3/T4 pipelined staging: 4-buffer LDS ring, 3 tiles in flight, counted
// s_waitcnt vmcnt(8) + raw s_barrier per tile (never drain to 0 mid-loop).
// r11's per-tile vmcnt(0)+__syncthreads() exposed the full ~1000cy L2 stage
// latency at 1 block/CU; counted waits let stages span 3 compute phases.
__global__ __launch_bounds__(256, 1) void k_mg(
    const float* __restrict__ mem, const float* __restrict__ eattr,
    const int* __restrict__ wnode, const int* __restrict__ wedge,
    const int* __restrict__ wsrc, const int* __restrict__ Mp,
    const u16* __restrict__ W1p, const float* __restrict__ b1,
    const u16* __restrict__ Wcat2p, const float* __restrict__ bias2,
    u16* __restrict__ xb) {
    __shared__ u16 lB[4][128 * 64];   // 64 KB ring
    __shared__ u16 h1l[64][136];      // padded rows -> 2-way-free banking

    const int tid = threadIdx.x;
    const int wid = tid >> 6, lane = tid & 63;
    const int lrow = lane & 15, lhi = lane >> 4;
    const int M = *Mp;
    const int arow0 = blockIdx.x * 64;
    if (arow0 >= M) return;

    const int rowg = arow0 + wid * 16 + lrow;
    const int rowc = min(rowg, M - 1);
    const int node = wnode[rowc];
    const int we = wedge[rowc];
    const int src = wsrc[rowc];

    // gather A fragments FIRST (older in vmcnt queue than stage loads, so the
    // compiler's gather waits don't force the staged tiles to retire)
    bf16x8 af[12];
#pragma unroll
    for (int ks = 0; ks < 12; ++ks) {
        int c = ks * 4 + lhi;
        const float* p;
        if (c < 16)      p = mem + (size_t)src * 128 + c * 8;
        else if (c < 32) p = mem + (size_t)node * 128 + (c - 16) * 8;
        else             p = eattr + (size_t)we * 128 + (c - 32) * 8;
        float4 v0 = *(const float4*)p;
        float4 v1 = *(const float4*)(p + 4);
        bf16x8 a;
        a[0] = (short)f2b(v0.x); a[1] = (short)f2b(v0.y);
        a[2] = (short)f2b(v0.z); a[3] = (short)f2b(v0.w);
        a[4] = (short)f2b(v1.x); a[5] = (short)f2b(v1.y);
        a[6] = (short)f2b(v1.z); a[7] = (short)f2b(v1.w);
        af[ks] = a;
    }

    // unified tile stream: t=0..5 -> W1p kt=t ; t=6..21 -> Wcat2p g=t-6
    auto stTile = [&](int t) {
        const u16* Bp; int K, rowoff, kt;
        if (t < 6) { Bp = W1p; K = 384; rowoff = 0; kt = t; }
        else { int g = t - 6; Bp = Wcat2p; K = 256; rowoff = (g >> 2) * 128; kt = g & 3; }
        u16* dst = (u16*)lB[t & 3];
#pragma unroll
        for (int i = 0; i < 4; ++i) {
            int chunk = i * 256 + wid * 64 + lane;
            int row = chunk >> 3, cc = chunk & 7;
            int ccs = cc ^ (row & 7);
            gld_lds16(Bp + (size_t)(rowoff + row) * K + kt * 64 + ccs * 8,
                      &dst[(i * 256 + wid * 64) * 8]);
        }
    };
    stTile(0); stTile(1); stTile(2);   // 12 loads/wave in flight

    // ---- GEMM1: tiles 0..5, acc1 ----
    f32x4 acc1[8] = {};
#pragma unroll
    for (int t = 0; t < 6; ++t) {
        asm volatile("s_waitcnt vmcnt(8)\ns_barrier" ::: "memory");
        stTile(t + 3);
        const u16* lBc = lB[t & 3];
#pragma unroll
        for (int ks = 0; ks < 2; ++ks) {
            bf16x8 bf[8];
#pragma unroll
            for (int n2 = 0; n2 < 8; ++n2) {
                int chunk = (ks * 4 + lhi) ^ (lrow & 7);
                bf[n2] = *(const bf16x8*)&lBc[(size_t)(n2 * 16 + lrow) * 64 + chunk * 8];
            }
#pragma unroll
            for (int n2 = 0; n2 < 8; ++n2)
                acc1[n2] = __builtin_amdgcn_mfma_f32_16x16x32_bf16(
                    bf[n2], af[t * 2 + ks], acc1[n2], 0, 0, 0);
        }
    }

    // h1 -> LDS (intra-wave layout round-trip; visibility ensured at next wait)
    {
        const int rl = wid * 16 + lrow;
#pragma unroll
        for (int n2 = 0; n2 < 8; ++n2) {
            int col = n2 * 16 + lhi * 4;
            float4 bv = *(const float4*)&b1[col];
            ushort4 o;
            o.x = f2b(fmaxf(acc1[n2][0] + bv.x, 0.f));
            o.y = f2b(fmaxf(acc1[n2][1] + bv.y, 0.f));
            o.z = f2b(fmaxf(acc1[n2][2] + bv.z, 0.f));
            o.w = f2b(fmaxf(acc1[n2][3] + bv.w, 0.f));
            *(ushort4*)&h1l[rl][col] = o;
        }
    }

    // ---- GEMM2 PASS A: global tiles 6..13 (quads 0,1 = R,Z) ----
    f32x4 accP[8] = {}, accQ[8] = {};
    bf16x8 af2[4];
#pragma unroll
    for (int tt = 0; tt < 8; ++tt) {
        if (tt == 0)
            asm volatile("s_waitcnt vmcnt(8) lgkmcnt(0)\ns_barrier" ::: "memory");
        else
            asm volatile("s_waitcnt vmcnt(8)\ns_barrier" ::: "memory");
        stTile(9 + tt);
        if (tt == 0) {
#pragma unroll
            for (int ks = 0; ks < 4; ++ks)
                af2[ks] = *(const bf16x8*)&h1l[wid * 16 + lrow][ks * 32 + lhi * 8];
        }
        const u16* lBc = lB[(6 + tt) & 3];
#pragma unroll
        for (int ks = 0; ks < 2; ++ks) {
            const int kk = (tt & 3) * 2 + ks;
            bf16x8 a = (kk < 4) ? af2[kk] : af[kk];
            bf16x8 bf[8];
#pragma unroll
            for (int n2 = 0; n2 < 8; ++n2) {
                int chunk = (ks * 4 + lhi) ^ (lrow & 7);
                bf[n2] = *(const bf16x8*)&lBc[(size_t)(n2 * 16 + lrow) * 64 + chunk * 8];
            }
            if (tt < 4) {
#pragma unroll
                for (int n2 = 0; n2 < 8; ++n2)
                    accP[n2] = __builtin_amdgcn_mfma_f32_16x16x32_bf16(
                        bf[n2], a, accP[n2], 0, 0, 0);
            } else {
#pragma unroll
                for (int n2 = 0; n2 < 8; ++n2)
                    accQ[n2] = __builtin_amdgcn_mfma_f32_16x16x32_bf16(
                        bf[n2], a, accQ[n2], 0, 0, 0);
            }
        }
    }

    // ---- between passes: r = sigmoid(R), z = sigmoid(Z) -> packed bf16 pairs ----
    unsigned rz[32];
#pragma unroll
    for (int n2 = 0; n2 < 8; ++n2) {
        int col = n2 * 16 + lhi * 4;
        float4 br = *(const float4*)&bias2[col];
        float4 bz = *(const float4*)&bias2[128 + col];
#pragma unroll
        for (int j = 0; j < 4; ++j) {
            float bR = (j == 0) ? br.x : (j == 1) ? br.y : (j == 2) ? br.z : br.w;
            float bZ = (j == 0) ? bz.x : (j == 1) ? bz.y : (j == 2) ? bz.z : bz.w;
            float r = 1.f / (1.f + expf(-(accP[n2][j] + bR)));
            float z = 1.f / (1.f + expf(-(accQ[n2][j] + bZ)));
            rz[n2 * 4 + j] = (unsigned)f2b(r) | ((unsigned)f2b(z) << 16);
        }
        accP[n2] = (f32x4){0.f, 0.f, 0.f, 0.f};
        accQ[n2] = (f32x4){0.f, 0.f, 0.f, 0.f};
    }

    // ---- GEMM2 PASS B: global tiles 14..21 (quads 2,3 = IN,HN) ----
#pragma unroll
    for (int tt = 0; tt < 8; ++tt) {
        if (tt <= 5)
            asm volatile("s_waitcnt vmcnt(8)\ns_barrier" ::: "memory");
        else if (tt == 6)
            asm volatile("s_waitcnt vmcnt(4)\ns_barrier" ::: "memory");
        else
            asm volatile("s_waitcnt vmcnt(0)\ns_barrier" ::: "memory");
        if (tt <= 4) stTile(17 + tt);
        const u16* lBc = lB[(14 + tt) & 3];
#pragma unroll
        for (int ks = 0; ks < 2; ++ks) {
            const int kk = (tt & 3) * 2 + ks;
            bf16x8 a = (kk < 4) ? af2[kk] : af[kk];
            bf16x8 bf[8];
#pragma unroll
            for (int n2 = 0; n2 < 8; ++n2) {
                int chunk = (ks * 4 + lhi) ^ (lrow & 7);
                bf[n2] = *(const bf16x8*)&lBc[(size_t)(n2 * 16 + lrow) * 64 + chunk * 8];
            }
            if (tt < 4) {
#pragma unroll
                for (int n2 = 0; n2 < 8; ++n2)
                    accP[n2] = __builtin_amdgcn_mfma_f32_16x16x32_bf16(
                        bf[n2], a, accP[n2], 0, 0, 0);
            } else {
#pragma unroll
                for (int n2 = 0; n2 < 8; ++n2)
                    accQ[n2] = __builtin_amdgcn_mfma_f32_16x16x32_bf16(
                        bf[n2], a, accQ[n2], 0, 0, 0);
            }
        }
    }

    // ---- GRU epilogue -> xb[node] (accP=IN, accQ=HN) ----
    if (rowg >= M) return;
#pragma unroll
    for (int n2 = 0; n2 < 8; ++n2) {
        int col = n2 * 16 + lhi * 4;
        float4 bn = *(const float4*)&bias2[256 + col];
        float4 bh = *(const float4*)&bias2[384 + col];
        float4 hv = *(const float4*)&mem[(size_t)node * 128 + col];
        ushort4 o;
#pragma unroll
        for (int j = 0; j < 4; ++j) {
            float bN = (j == 0) ? bn.x : (j == 1) ? bn.y : (j == 2) ? bn.z : bn.w;
            float bH = (j == 0) ? bh.x : (j == 1) ? bh.y : (j == 2) ? bh.z : bh.w;
            float hj = (j == 0) ? hv.x : (j == 1) ? hv.y : (j == 2) ? hv.z : hv.w;
            unsigned p = rz[n2 * 4 + j];
            float r = b2f((u16)(p & 0xffff));
            float z = b2f((u16)(p >> 16));
            float n = tanhf(accP[n2][j] + bN + r * (accQ[n2][j] + bH));
            u16 res = f2b((1.f - z) * n + z * hj);
            if (j == 0) o.x = res; else if (j == 1) o.y = res;
            else if (j == 2) o.z = res; else o.w = res;
        }
        *(ushort4*)&xb[(size_t)node * 128 + col] = o;
    }
}

// ================= proj GEMM: r6 template + pipelined staging (4-buffer ring) =========
template <int K, int NQUAD>
__global__ __launch_bounds__(256, 1) void k_proj(
    const u16* __restrict__ A, const u16* __restrict__ Bp,
    const float* __restrict__ bias, int Mmax,
    u16* __restrict__ qb, u16* __restrict__ kb, u16* __restrict__ vcb,
    float* __restrict__ outf) {
    constexpr int KT = K / 64;          // 2
    constexpr int NT = NQUAD * KT;      // 12
    constexpr int NKS = K / 32;         // 4
    constexpr int CPR = K / 8;          // 16
    __shared__ u16 lA[64 * K];          // 16 KB
    __shared__ u16 lB[4][128 * 64];     // 64 KB ring

    const int tid = threadIdx.x;
    const int wid = tid >> 6, lane = tid & 63;
    const int lrow = lane & 15, lhi = lane >> 4;
    const int arow0 = blockIdx.x * 64;

#pragma unroll
    for (int i = 0; i < (64 * CPR) / 256; ++i) {
        int chunk = i * 256 + wid * 64 + lane;
        int row = chunk / CPR, cc = chunk % CPR;
        int ccs = (cc & ~7) | ((cc ^ row) & 7);
        gld_lds16(A + (size_t)(arow0 + row) * K + ccs * 8, &lA[(i * 256 + wid * 64) * 8]);
    }
    auto stTile = [&](int t) {
        int q = t / KT, kt = t - q * KT;
        u16* dst = (u16*)lB[t & 3];
#pragma unroll
        for (int i = 0; i < 4; ++i) {
            int chunk = i * 256 + wid * 64 + lane;
            int row = chunk >> 3, cc = chunk & 7;
            int ccs = cc ^ (row & 7);
            gld_lds16(Bp + (size_t)(q * 128 + row) * K + kt * 64 + ccs * 8,
                      &dst[(i * 256 + wid * 64) * 8]);
        }
    };
    stTile(0); stTile(1); stTile(2);
    // wait for lA (this wave's 4 oldest loads) + cross-wave barrier; 12 tile loads stay in flight
    asm volatile("s_waitcnt vmcnt(12)\ns_barrier" ::: "memory");

    bf16x8 af[NKS];
#pragma unroll
    for (int ks = 0; ks < NKS; ++ks) {
        int chunk = ks * 4 + lhi;
        int ccs = (chunk & ~7) | ((chunk ^ lrow) & 7);
        af[ks] = *(const bf16x8*)&lA[(size_t)(wid * 16 + lrow) * K + ccs * 8];
    }

    f32x4 acc[NQUAD][8] = {};
#pragma unroll
    for (int t = 0; t < NT; ++t) {
        if (t <= NT - 3)
            asm volatile("s_waitcnt vmcnt(8)\ns_barrier" ::: "memory");
        else if (t == NT - 2)
            asm volatile("s_waitcnt vmcnt(4)\ns_barrier" ::: "memory");
        else
            asm volatile("s_waitcnt vmcnt(0)\ns_barrier" ::: "memory");
        if (t + 3 < NT) stTile(t + 3);
        const int q = t / KT, kt = t - q * KT;
        const u16* lBc = lB[t & 3];
#pragma unroll
        for (int ks = 0; ks < 2; ++ks) {
            bf16x8 bf[8];
#pragma unroll
            for (int n2 = 0; n2 < 8; ++n2) {
                int chunk = (ks * 4 + lhi) ^ (lrow & 7);
                bf[n2] = *(const bf16x8*)&lBc[(size_t)(n2 * 16 + lrow) * 64 + chunk * 8];
            }
#pragma unroll
            for (int n2 = 0; n2 < 8; ++n2)
                acc[q][n2] = __builtin_amdgcn_mfma_f32_16x16x32_bf16(
                    bf[n2], af[kt * 2 + ks], acc[q][n2], 0, 0, 0);
        }
    }

    const int rowg = arow0 + wid * 16 + lrow;
    if (rowg >= Mmax) return;

#pragma unroll
    for (int q = 0; q < NQUAD; ++q) {
#pragma unroll
        for (int n2 = 0; n2 < 8; ++n2) {
            int colg = q * 128 + n2 * 16 + lhi * 4;
            if (colg >= 704) continue;
            float4 bv = *(const float4*)&bias[colg];
            float v0 = acc[q][n2][0] + bv.x, v1 = acc[q][n2][1] + bv.y;
            float v2 = acc[q][n2][2] + bv.z, v3 = acc[q][n2][3] + bv.w;
            if (colg < 640) {
                ushort4 o;
                o.x = f2b(v0); o.y = f2b(v1); o.z = f2b(v2); o.w = f2b(v3);
                if (colg < 256)
                    *(ushort4*)&qb[(size_t)rowg * 256 + colg] = o;
                else if (colg < 512)
                    *(ushort4*)&kb[(size_t)rowg * 256 + (colg - 256)] = o;
                else
                    *(ushort4*)&vcb[(size_t)rowg * 128 + (colg - 512)] = o;
            } else {
                float4 o; o.x = v0; o.y = v1; o.z = v2; o.w = v3;
                *(float4*)&outf[(size_t)rowg * 64 + (colg - 640)] = o;
            }
        }
    }
}

// ---------------- CSR attention: one wave per dst, no atomics ----------------
__global__ __launch_bounds__(256) void k_attn(
    const u16* __restrict__ qB, const u16* __restrict__ kB, const u16* __restrict__ vcB,
    const int* __restrict__ startA, const int* __restrict__ deg,
    const int* __restrict__ esrc, float* __restrict__ out) {
    int wid = threadIdx.x >> 6, lane = threadIdx.x & 63;
    int dst = blockIdx.x * 4 + wid;
    if (dst >= N_NODES) return;
    int d = deg[dst];
    if (d == 0) return;
    int st = startA[dst];

    ushort4 qv = *(const ushort4*)&qB[(size_t)dst * 256 + lane * 4];
    float q0 = b2f(qv.x), q1 = b2f(qv.y), q2 = b2f(qv.z), q3 = b2f(qv.w);
    const float inv = 0.08838834764831845f;  // 1/sqrt(128)

    float s0 = 0.f, s1 = 0.f, accA = 0.f, accB = 0.f;
    for (int p = st; p < st + d; ++p) {
        int src = esrc[p];
        ushort4 kv = *(const ushort4*)&kB[(size_t)src * 256 + lane * 4];
        float pp = q0 * b2f(kv.x) + q1 * b2f(kv.y) + q2 * b2f(kv.z) + q3 * b2f(kv.w);
        pp += __shfl_xor(pp, 1);
        pp += __shfl_xor(pp, 2);
        pp += __shfl_xor(pp, 4);
        pp += __shfl_xor(pp, 8);
        pp += __shfl_xor(pp, 16);
        float e = expf(pp * inv);
        float eo = __shfl_xor(e, 32);
        float e0 = (lane < 32) ? e : eo;
        float e1 = (lane < 32) ? eo : e;
        s0 += e0; s1 += e1;
        float v0 = b2f(vcB[(size_t)src * 128 + lane]);
        float v1 = b2f(vcB[(size_t)src * 128 + 64 + lane]);
        accA += e0 * v0;
        accB += e1 * v1;
    }
    float* op = out + (size_t)dst * 64 + lane;
    *op += accA / s0 + accB / s1;
}

extern "C" void kernel_launch(void* const* d_in, const int* in_sizes, int n_in,
                              void* d_out, int out_size, void* d_ws, size_t ws_size,
                              hipStream_t stream) {
    const float* memory = (const float*)d_in[0];
    const float* W1 = (const float*)d_in[1];  const float* b1 = (const float*)d_in[2];
    const float* W2 = (const float*)d_in[3];  const float* b2 = (const float*)d_in[4];
    const float* Wih = (const float*)d_in[5]; const float* Whh = (const float*)d_in[6];
    const float* bih = (const float*)d_in[7]; const float* bhh = (const float*)d_in[8];
    const float* Wq = (const float*)d_in[9];  const float* bq = (const float*)d_in[10];
    const float* Wk = (const float*)d_in[11]; const float* bk = (const float*)d_in[12];
    const float* Wv = (const float*)d_in[13]; const float* bv = (const float*)d_in[14];
    const float* Ws = (const float*)d_in[15]; const float* bs = (const float*)d_in[16];
    const float* Wc = (const float*)d_in[17]; const float* bc = (const float*)d_in[18];
    const float* eattr = (const float*)d_in[19];
    const int* ei = (const int*)d_in[21];
    float* out = (float*)d_out;

    char* ws = (char*)d_ws;
    size_t off = 0;
    auto alloc = [&](size_t bytes) -> char* {
        char* p = ws + off;
        off = (off + bytes + 255) & ~(size_t)255;
        return p;
    };
    u16* xb = (u16*)alloc((size_t)NPAD * 128 * 2);
    u16* qb = (u16*)alloc((size_t)NPAD * 256 * 2);
    u16* kb = (u16*)alloc((size_t)NPAD * 256 * 2);
    u16* vcb = (u16*)alloc((size_t)NPAD * 128 * 2);
    int* winner = (int*)alloc((size_t)N_NODES * 4);
    int* wnode = (int*)alloc((size_t)N_NODES * 4);
    int* wedge = (int*)alloc((size_t)N_NODES * 4);
    int* wsrc = (int*)alloc((size_t)N_NODES * 4);
    int* deg = (int*)alloc((size_t)N_NODES * 4);
    int* startA = (int*)alloc((size_t)N_NODES * 4);
    int* cursor = (int*)alloc((size_t)N_NODES * 4);
    int* esrc = (int*)alloc((size_t)E_EDGES * 4);
    int* counters = (int*)alloc(256);
    u16* W1p = (u16*)alloc(49152 * 2);
    u16* Wcat2p = (u16*)alloc(131072 * 2);
    u16* Wprojp = (u16*)alloc(98304 * 2);
    float* bias2 = (float*)alloc(512 * 4);
    float* bproj = (float*)alloc(768 * 4);
    (void)ws_size; (void)in_sizes; (void)n_in; (void)out_size;

    int* wcount = counters;  // counters[0]=wcount, counters[1]=etot

    hipLaunchKernelGGL(k_init, dim3(391), dim3(256), 0, stream, winner, deg, counters);
    hipLaunchKernelGGL(k_edges, dim3(1563), dim3(256), 0, stream, ei, winner, deg);
    hipLaunchKernelGGL(k_nodes, dim3(391), dim3(256), 0, stream,
                       winner, deg, ei, wnode, wedge, wsrc, counters, startA, cursor);
    hipLaunchKernelGGL(k_fill, dim3(1563), dim3(256), 0, stream, ei, cursor, esrc);
    hipLaunchKernelGGL(k_pack, dim3(579), dim3(256), 0, stream,
                       W1, Wq, Wk, Wv, Ws, Wc, bq, bk, bv, bs, bc, W1p, Wprojp, bproj);
    hipLaunchKernelGGL(k_fold, dim3(512), dim3(128), 0, stream,
                       W2, Wih, Whh, bih, bhh, b2, Wcat2p, bias2);
    hipLaunchKernelGGL(k_xinit, dim3(12500), dim3(256), 0, stream, memory, winner, xb);
    // fused gather + MLP + GRU for winner rows
    hipLaunchKernelGGL(k_mg, dim3(1564), dim3(256), 0, stream,
                       memory, eattr, wnode, wedge, wsrc, wcount,
                       W1p, b1, Wcat2p, bias2, xb);
    // proj: [q|k|vc|skip] = xb @ Wproj + bproj  (skip -> out, f32)
    hipLaunchKernelGGL((k_proj<128, 6>), dim3(1564), dim3(256), 0, stream,
                       xb, Wprojp, bproj, N_NODES, qb, kb, vcb, out);
    // CSR attention: out[dst] += sum(alpha * vc[src]) per head, no atomics
    hipLaunchKernelGGL(k_attn, dim3(25000), dim3(256), 0, stream,
                       qb, kb, vcb, startA, deg, esrc, out);
}